// Round 8
// baseline (122.753 us; speedup 1.0000x reference)
//
#include <hip/hip_runtime.h>
#include <stdint.h>

// Problem constants: B=2, L=2048, N=4, D=2048
#define NC       8192
#define D_       2048
#define NOUTS    24
#define WPAD     8224        // fallback path: padded row stride for transposed w
#define NB       32          // padded output count for MFMA (24 -> 32, cols 24..31 zero)

typedef __attribute__((ext_vector_type(8))) short short8;
typedef __attribute__((ext_vector_type(4))) float f32x4;

// round-to-nearest-even f32 -> bf16 bits
__device__ __forceinline__ uint16_t f32_to_bf16_bits(float f) {
    uint32_t u = __builtin_bit_cast(uint32_t, f);
    return (uint16_t)((u + 0x7FFFu + ((u >> 16) & 1u)) >> 16);
}

// ======================= MFMA split path =======================

// prep: wb[o][c] = bf16(gamma[c] * w[c][o]), o in [0,32) with 24..31 zeroed.
__global__ void prep_wb_kernel(const float* __restrict__ w,
                               const float* __restrict__ gamma,
                               uint16_t* __restrict__ wb) {
    int idx = blockIdx.x * blockDim.x + threadIdx.x;
    if (idx >= NB * NC) return;
    int o = idx / NC;
    int c = idx - o * NC;            // consecutive threads -> consecutive c
    float v = (o < NOUTS) ? gamma[c] * w[c * NOUTS + o] : 0.0f;
    wb[o * NC + c] = f32_to_bf16_bits(v);
}

// K1: [16 rows x 24 outs] per wave via mfma_f32_16x16x32_bf16 (two 16-col tiles).
// Round-7 post-mortem: ~38us vs 21us HBM floor; in-flight bytes/CU ~4KB at 16
// waves/CU with ~50% load-issue duty. Fix: nslices=32 (32 waves/CU demand) and
// NO launch_bounds (the (256,4) bound capped occupancy at 4 waves/SIMD; ~90-reg
// demand sustains 5/SIMD). acc is 8 VGPRs -- no round-4-style spill pressure.
__global__ void gemv_mfma_kernel(
    const float* __restrict__ h, const uint16_t* __restrict__ wb,
    float* __restrict__ part, int nrows, int nslices)
{
    const int lane = threadIdx.x & 63;
    const int unit = blockIdx.x * 4 + (threadIdx.x >> 6);
    const int nrg  = nrows >> 4;
    const int rg   = unit % nrg;           // consecutive units share slice s -> wb L1/L2 reuse
    const int s    = unit / nrg;
    if (s >= nslices) return;
    const int r0 = rg * 16;
    const int kw = NC / nslices;           // k-extent per slice (multiple of 32)
    const int k0 = s * kw;

    const int arow = lane & 15;
    const int kgrp = (lane >> 4) << 3;     // 0,8,16,24
    const float*    hA  = h  + (size_t)(r0 + arow) * NC + k0 + kgrp;
    const uint16_t* wB0 = wb + (size_t)arow        * NC + k0 + kgrp;
    const uint16_t* wB1 = wb + (size_t)(arow + 16) * NC + k0 + kgrp;

    f32x4 acc0 = {0.f, 0.f, 0.f, 0.f};
    f32x4 acc1 = {0.f, 0.f, 0.f, 0.f};
    float ss = 0.0f;

#pragma unroll 4
    for (int k = 0; k < kw; k += 32) {
        const float4 a_lo = *reinterpret_cast<const float4*>(hA + k);
        const float4 a_hi = *reinterpret_cast<const float4*>(hA + k + 4);
        const short8 b0 = *reinterpret_cast<const short8*>(wB0 + k);
        const short8 b1 = *reinterpret_cast<const short8*>(wB1 + k);

        ss += a_lo.x*a_lo.x + a_lo.y*a_lo.y + a_lo.z*a_lo.z + a_lo.w*a_lo.w
            + a_hi.x*a_hi.x + a_hi.y*a_hi.y + a_hi.z*a_hi.z + a_hi.w*a_hi.w;

        short8 av;
        av[0] = (short)f32_to_bf16_bits(a_lo.x);
        av[1] = (short)f32_to_bf16_bits(a_lo.y);
        av[2] = (short)f32_to_bf16_bits(a_lo.z);
        av[3] = (short)f32_to_bf16_bits(a_lo.w);
        av[4] = (short)f32_to_bf16_bits(a_hi.x);
        av[5] = (short)f32_to_bf16_bits(a_hi.y);
        av[6] = (short)f32_to_bf16_bits(a_hi.z);
        av[7] = (short)f32_to_bf16_bits(a_hi.w);

        acc0 = __builtin_amdgcn_mfma_f32_16x16x32_bf16(av, b0, acc0, 0, 0, 0);
        acc1 = __builtin_amdgcn_mfma_f32_16x16x32_bf16(av, b1, acc1, 0, 0, 0);
    }

    // sumsq: combine the 4 lane-groups holding the same row
    ss += __shfl_xor(ss, 16, 64);
    ss += __shfl_xor(ss, 32, 64);

    // C layout (HW-verified): col = lane&15, row = (lane>>4)*4 + reg
    const int o0   = lane & 15;
    const int crow = r0 + ((lane >> 4) << 2);
    float* pbase = part + (size_t)s * 25 * nrows;
#pragma unroll
    for (int i = 0; i < 4; ++i)
        pbase[(size_t)o0 * nrows + crow + i] = acc0[i];
    if (o0 < NOUTS - 16) {                 // cols 16..23 from tile 1
#pragma unroll
        for (int i = 0; i < 4; ++i)
            pbase[(size_t)(o0 + 16) * nrows + crow + i] = acc1[i];
    }
    if (lane < 16)                         // slot 24 = sumsq, lane == row
        pbase[(size_t)24 * nrows + r0 + lane] = ss;
}

// K2: one wave per row (round-6: thread-per-row at 64 waves total was
// latency-bound). Lane (o = lane&31, g = lane>>5) sums half the slices ->
// shfl_xor(32) fold -> 25 shfl broadcasts -> all lanes run the 4x4 Sinkhorn
// redundantly in registers; lanes 0..15 write C coalesced.
__global__ void sinkhorn_wave_kernel(const float* __restrict__ part,
                                     const float* __restrict__ alpha,
                                     const float* __restrict__ beta,
                                     const int* __restrict__ it_ptr,
                                     float* __restrict__ Cbuf, int nrows, int nslices)
{
    const int lane = threadIdx.x & 63;
    const int row  = blockIdx.x * 4 + (threadIdx.x >> 6);
    if (row >= nrows) return;

    const int o = lane & 31;               // output slot, active for o < 25
    const int g = lane >> 5;               // slice-half 0/1
    float acc = 0.0f;
    if (o < 25) {
#pragma unroll 4
        for (int s = g; s < nslices; s += 2)
            acc += part[((size_t)s * 25 + o) * nrows + row];
    }
    acc += __shfl_xor(acc, 32, 64);        // fold the two slice-halves

    float H[25];
#pragma unroll
    for (int i = 0; i < 25; ++i) H[i] = __shfl(acc, i, 64);   // lane i holds H[i]

    const float r_ = sqrtf((float)NC / H[24]);       // 1/r
    const float a0 = alpha[0], a1 = alpha[1], a2 = alpha[2];

    float Hpre[4], Hpost[4], M[16];
#pragma unroll
    for (int n = 0; n < 4; ++n) {
        const float x = r_ * H[n] * a0 + beta[n];
        Hpre[n] = __builtin_amdgcn_rcpf(1.0f + __expf(-x));
        const float y = r_ * H[4 + n] * a1 + beta[4 + n];
        Hpost[n] = 2.0f * __builtin_amdgcn_rcpf(1.0f + __expf(-y));
    }
#pragma unroll
    for (int k = 0; k < 16; ++k)
        M[k] = __expf(r_ * H[8 + k] * a2 + beta[8 + k]);

    float u[4] = {1.f, 1.f, 1.f, 1.f}, vv[4] = {1.f, 1.f, 1.f, 1.f};
    int iters = *it_ptr;
    if (iters < 0 || iters > 10000) {                // robustness if scalar arrives float-encoded
        const float f = __int_as_float(iters);
        iters = (f >= 0.0f && f < 10000.0f) ? (int)f : 10;
    }
    for (int it = 0; it < iters; ++it) {
#pragma unroll
        for (int i = 0; i < 4; ++i)
            u[i] = __builtin_amdgcn_rcpf(
                M[4*i+0]*vv[0] + M[4*i+1]*vv[1] + M[4*i+2]*vv[2] + M[4*i+3]*vv[3] + 1e-8f);
#pragma unroll
        for (int j2 = 0; j2 < 4; ++j2)
            vv[j2] = __builtin_amdgcn_rcpf(
                M[j2]*u[0] + M[4+j2]*u[1] + M[8+j2]*u[2] + M[12+j2]*u[3] + 1e-8f);
    }

    if (lane < 16) {                       // C[m][n] = Hpost[m]*Hpre[n] + P[m][n]
        const int m = lane >> 2, n = lane & 3;
        Cbuf[(size_t)row * 16 + lane] = Hpost[m] * Hpre[n] + u[m] * M[lane] * vv[n];
    }
}

// K3: pure streaming mix: out[m,d] = sum_n C[m][n] * h[n,d]. One block per row.
__global__ __launch_bounds__(256, 8) void mix_kernel(
    const float* __restrict__ h, const float* __restrict__ Cbuf,
    float* __restrict__ out)
{
    const int row = blockIdx.x;
    const float* cr = Cbuf + (size_t)row * 16;
    float C[16];
#pragma unroll
    for (int k = 0; k < 16; ++k) C[k] = cr[k];       // wave-uniform -> scalar loads

    const float* hr = h + (size_t)row * NC;
    float* orow = out + (size_t)row * NC;
#pragma unroll
    for (int t = 0; t < 2; ++t) {
        const int d0 = t * 1024 + (threadIdx.x << 2);
        float4 hn[4];
#pragma unroll
        for (int n = 0; n < 4; ++n)
            hn[n] = *reinterpret_cast<const float4*>(hr + n * D_ + d0);
#pragma unroll
        for (int m = 0; m < 4; ++m) {
            float4 o4;
            o4.x = C[4*m+0]*hn[0].x + C[4*m+1]*hn[1].x + C[4*m+2]*hn[2].x + C[4*m+3]*hn[3].x;
            o4.y = C[4*m+0]*hn[0].y + C[4*m+1]*hn[1].y + C[4*m+2]*hn[2].y + C[4*m+3]*hn[3].y;
            o4.z = C[4*m+0]*hn[0].z + C[4*m+1]*hn[1].z + C[4*m+2]*hn[2].z + C[4*m+3]*hn[3].z;
            o4.w = C[4*m+0]*hn[0].w + C[4*m+1]*hn[1].w + C[4*m+2]*hn[2].w + C[4*m+3]*hn[3].w;
            *reinterpret_cast<float4*>(orow + m * D_ + d0) = o4;
        }
    }
}

// ======================= fallback (round-2, known-passing) =======================

__global__ void prep_w_kernel(const float* __restrict__ w, float* __restrict__ wp) {
    int idx = blockIdx.x * blockDim.x + threadIdx.x;
    if (idx >= NOUTS * NC) return;
    int o = idx / NC;
    int c = idx - o * NC;
    wp[o * WPAD + c] = w[c * NOUTS + o];
}

__global__ __launch_bounds__(256, 4) void fused_kernel(
    const float* __restrict__ h, const float* __restrict__ gamma,
    const float* __restrict__ wp, const float* __restrict__ alpha,
    const float* __restrict__ beta, const int* __restrict__ it_ptr,
    float* __restrict__ out, int nrows)
{
    const int wave = threadIdx.x >> 6;
    const int lane = threadIdx.x & 63;
    const int row  = (blockIdx.x << 2) | wave;
    if (row >= nrows) return;
    const float* hrow = h + (size_t)row * NC;

    float acc[NOUTS];
#pragma unroll
    for (int o = 0; o < NOUTS; ++o) acc[o] = 0.0f;
    float sumsq = 0.0f;
    const int base = lane << 2;
#pragma unroll 2
    for (int j = 0; j < 32; ++j) {
        const int c0 = base + (j << 8);
        const float4 h4 = *reinterpret_cast<const float4*>(hrow + c0);
        const float4 g4 = *reinterpret_cast<const float4*>(gamma + c0);
        sumsq += h4.x*h4.x + h4.y*h4.y + h4.z*h4.z + h4.w*h4.w;
        const float v0 = h4.x*g4.x, v1 = h4.y*g4.y, v2 = h4.z*g4.z, v3 = h4.w*g4.w;
#pragma unroll
        for (int o = 0; o < NOUTS; ++o) {
            const float4 w4 = *reinterpret_cast<const float4*>(wp + o * WPAD + c0);
            acc[o] += v0*w4.x + v1*w4.y + v2*w4.z + v3*w4.w;
        }
    }
#pragma unroll
    for (int m = 1; m < 64; m <<= 1) {
        sumsq += __shfl_xor(sumsq, m, 64);
#pragma unroll
        for (int o = 0; o < NOUTS; ++o) acc[o] += __shfl_xor(acc[o], m, 64);
    }
    const float r_ = sqrtf((float)NC / sumsq);
    const float a0 = alpha[0], a1 = alpha[1], a2 = alpha[2];
    float Hpre[4], Hpost[4], M[16];
#pragma unroll
    for (int n = 0; n < 4; ++n) {
        const float x = r_ * acc[n] * a0 + beta[n];
        Hpre[n] = __builtin_amdgcn_rcpf(1.0f + __expf(-x));
        const float y = r_ * acc[4 + n] * a1 + beta[4 + n];
        Hpost[n] = 2.0f * __builtin_amdgcn_rcpf(1.0f + __expf(-y));
    }
#pragma unroll
    for (int k = 0; k < 16; ++k)
        M[k] = __expf(r_ * acc[8 + k] * a2 + beta[8 + k]);
    float u[4] = {1.f,1.f,1.f,1.f}, v[4] = {1.f,1.f,1.f,1.f};
    int iters = *it_ptr;
    if (iters < 0 || iters > 10000) {
        const float f = __int_as_float(iters);
        iters = (f >= 0.0f && f < 10000.0f) ? (int)f : 10;
    }
    for (int it = 0; it < iters; ++it) {
#pragma unroll
        for (int i = 0; i < 4; ++i)
            u[i] = __builtin_amdgcn_rcpf(M[4*i+0]*v[0] + M[4*i+1]*v[1] + M[4*i+2]*v[2] + M[4*i+3]*v[3] + 1e-8f);
#pragma unroll
        for (int j2 = 0; j2 < 4; ++j2)
            v[j2] = __builtin_amdgcn_rcpf(M[j2]*u[0] + M[4+j2]*u[1] + M[8+j2]*u[2] + M[12+j2]*u[3] + 1e-8f);
    }
    float P[16];
#pragma unroll
    for (int i = 0; i < 4; ++i)
#pragma unroll
        for (int j2 = 0; j2 < 4; ++j2)
            P[4*i + j2] = u[i] * M[4*i + j2] * v[j2];
    float* orow = out + (size_t)row * NC;
#pragma unroll 2
    for (int t = 0; t < 8; ++t) {
        const int d0 = base + (t << 8);
        float hn[4][4];
#pragma unroll
        for (int n = 0; n < 4; ++n) {
            const float4 x4 = *reinterpret_cast<const float4*>(hrow + n * D_ + d0);
            hn[n][0]=x4.x; hn[n][1]=x4.y; hn[n][2]=x4.z; hn[n][3]=x4.w;
        }
        float hp[4];
#pragma unroll
        for (int k = 0; k < 4; ++k)
            hp[k] = Hpre[0]*hn[0][k] + Hpre[1]*hn[1][k] + Hpre[2]*hn[2][k] + Hpre[3]*hn[3][k];
#pragma unroll
        for (int m = 0; m < 4; ++m) {
            float4 o4;
            o4.x = Hpost[m]*hp[0] + P[4*m+0]*hn[0][0] + P[4*m+1]*hn[1][0] + P[4*m+2]*hn[2][0] + P[4*m+3]*hn[3][0];
            o4.y = Hpost[m]*hp[1] + P[4*m+0]*hn[0][1] + P[4*m+1]*hn[1][1] + P[4*m+2]*hn[2][1] + P[4*m+3]*hn[3][1];
            o4.z = Hpost[m]*hp[2] + P[4*m+0]*hn[0][2] + P[4*m+1]*hn[1][2] + P[4*m+2]*hn[2][2] + P[4*m+3]*hn[3][2];
            o4.w = Hpost[m]*hp[3] + P[4*m+0]*hn[0][3] + P[4*m+1]*hn[1][3] + P[4*m+2]*hn[2][3] + P[4*m+3]*hn[3][3];
            *reinterpret_cast<float4*>(orow + m * D_ + d0) = o4;
        }
    }
}

// ======================= launch =======================

extern "C" void kernel_launch(void* const* d_in, const int* in_sizes, int n_in,
                              void* d_out, int out_size, void* d_ws, size_t ws_size,
                              hipStream_t stream) {
    const float* h     = (const float*)d_in[0];
    const float* gamma = (const float*)d_in[1];
    const float* w     = (const float*)d_in[2];
    const float* alpha = (const float*)d_in[3];
    const float* beta  = (const float*)d_in[4];
    const int*   itp   = (const int*)d_in[5];
    float*       out   = (float*)d_out;

    const int nrows = in_sizes[0] / NC;                       // 4096

    const size_t wb_bytes = (size_t)NB * NC * 2;              // 512 KB bf16 w
    const size_t c_bytes  = (size_t)nrows * 16 * 4;           // 256 KB

    int nslices = 0;
    if ((nrows % 16) == 0) {
        for (int cand = 32; cand >= 4; cand >>= 1) {          // prefer 32 (round-7: occupancy-limited MLP)
            const size_t pb = (size_t)cand * 25 * nrows * 4;
            if (ws_size >= wb_bytes + pb + c_bytes) { nslices = cand; break; }
        }
    }

    if (nslices) {
        uint16_t* wb   = (uint16_t*)d_ws;
        float*    part = (float*)((char*)d_ws + wb_bytes);
        float*    Cbuf = (float*)((char*)d_ws + wb_bytes + (size_t)nslices * 25 * nrows * 4);

        const int units = (nrows / 16) * nslices;
        prep_wb_kernel<<<(NB * NC + 255) / 256, 256, 0, stream>>>(w, gamma, wb);
        gemv_mfma_kernel<<<(units + 3) / 4, 256, 0, stream>>>(h, wb, part, nrows, nslices);
        sinkhorn_wave_kernel<<<(nrows + 3) / 4, 256, 0, stream>>>(part, alpha, beta, itp, Cbuf, nrows, nslices);
        mix_kernel<<<nrows, 256, 0, stream>>>(h, Cbuf, out);
    } else {
        float* wp = (float*)d_ws;
        prep_w_kernel<<<(NOUTS * NC + 255) / 256, 256, 0, stream>>>(w, wp);
        fused_kernel<<<(nrows + 3) / 4, 256, 0, stream>>>(h, gamma, wp, alpha, beta, itp, out, nrows);
    }
}

// Round 10
// 118.084 us; speedup vs baseline: 1.0395x; 1.0395x over previous
//
#include <hip/hip_runtime.h>
#include <hip/hip_bf16.h>
#include <stdint.h>

// Problem constants: B=2, L=2048, N=4, D=2048
#define NC       8192
#define D_       2048
#define NOUTS    24
#define WPAD     8224        // fallback path: padded row stride for transposed w
#define NB       32          // padded output count for MFMA (24 -> 32, cols 24..31 zero)

typedef __attribute__((ext_vector_type(8))) short short8;
typedef __attribute__((ext_vector_type(4))) float f32x4;

// round-to-nearest-even f32 -> bf16 bits (prep path; not hot)
__device__ __forceinline__ uint16_t f32_to_bf16_bits(float f) {
    uint32_t u = __builtin_bit_cast(uint32_t, f);
    return (uint16_t)((u + 0x7FFFu + ((u >> 16) & 1u)) >> 16);
}

// hot path: 2 floats -> packed bf16 dword via v_cvt_pk_bf16_f32 (RNE, 1 op).
// Round-9 fix: __builtin_bit_cast rejects __hip_bfloat162 (not trivially
// copyable) -> type-pun through a union instead.
__device__ __forceinline__ uint32_t pk_bf16(float lo, float hi) {
    union { __hip_bfloat162 b; uint32_t u; } cv;
    cv.b = __float22bfloat162_rn(make_float2(lo, hi));
    return cv.u;
}

// ======================= MFMA split path =======================

// prep: wb[o][c] = bf16(gamma[c] * w[c][o]), o in [0,32) with 24..31 zeroed.
__global__ void prep_wb_kernel(const float* __restrict__ w,
                               const float* __restrict__ gamma,
                               uint16_t* __restrict__ wb) {
    int idx = blockIdx.x * blockDim.x + threadIdx.x;
    if (idx >= NB * NC) return;
    int o = idx / NC;
    int c = idx - o * NC;            // consecutive threads -> consecutive c
    float v = (o < NOUTS) ? gamma[c] * w[c * NOUTS + o] : 0.0f;
    wb[o * NC + c] = f32_to_bf16_bits(v);
}

// K1: [16 rows x 24 outs] per wave via mfma_f32_16x16x32_bf16 (two 16-col tiles).
// Round-8 post-mortem: nslices=32 + no-bounds REGRESSED (+17us) -> keep the
// measured-good round-7 geometry: nslices=16, launch_bounds(256,4).
// Round-9/10 change: A-fragment conversion via v_cvt_pk_bf16_f32 (4 ops/iter)
// instead of the manual bit-twiddle (~45 ops/iter) -- the VALU chain between
// load bursts was throttling the load-issue duty cycle.
__global__ __launch_bounds__(256, 4) void gemv_mfma_kernel(
    const float* __restrict__ h, const uint16_t* __restrict__ wb,
    float* __restrict__ part, int nrows, int nslices)
{
    const int lane = threadIdx.x & 63;
    const int unit = blockIdx.x * 4 + (threadIdx.x >> 6);
    const int nrg  = nrows >> 4;
    const int rg   = unit % nrg;           // consecutive units share slice s -> wb L1/L2 reuse
    const int s    = unit / nrg;
    if (s >= nslices) return;
    const int r0 = rg * 16;
    const int kw = NC / nslices;           // k-extent per slice (multiple of 32)
    const int k0 = s * kw;

    const int arow = lane & 15;
    const int kgrp = (lane >> 4) << 3;     // 0,8,16,24
    const float*    hA  = h  + (size_t)(r0 + arow) * NC + k0 + kgrp;
    const uint16_t* wB0 = wb + (size_t)arow        * NC + k0 + kgrp;
    const uint16_t* wB1 = wb + (size_t)(arow + 16) * NC + k0 + kgrp;

    f32x4 acc0 = {0.f, 0.f, 0.f, 0.f};
    f32x4 acc1 = {0.f, 0.f, 0.f, 0.f};
    float ss = 0.0f;

    union AV { uint32_t u[4]; short8 s8; };

#pragma unroll 4
    for (int k = 0; k < kw; k += 32) {
        const float4 a_lo = *reinterpret_cast<const float4*>(hA + k);
        const float4 a_hi = *reinterpret_cast<const float4*>(hA + k + 4);
        const short8 b0 = *reinterpret_cast<const short8*>(wB0 + k);
        const short8 b1 = *reinterpret_cast<const short8*>(wB1 + k);

        ss += a_lo.x*a_lo.x + a_lo.y*a_lo.y + a_lo.z*a_lo.z + a_lo.w*a_lo.w
            + a_hi.x*a_hi.x + a_hi.y*a_hi.y + a_hi.z*a_hi.z + a_hi.w*a_hi.w;

        AV av;
        av.u[0] = pk_bf16(a_lo.x, a_lo.y);
        av.u[1] = pk_bf16(a_lo.z, a_lo.w);
        av.u[2] = pk_bf16(a_hi.x, a_hi.y);
        av.u[3] = pk_bf16(a_hi.z, a_hi.w);

        acc0 = __builtin_amdgcn_mfma_f32_16x16x32_bf16(av.s8, b0, acc0, 0, 0, 0);
        acc1 = __builtin_amdgcn_mfma_f32_16x16x32_bf16(av.s8, b1, acc1, 0, 0, 0);
    }

    // sumsq: combine the 4 lane-groups holding the same row
    ss += __shfl_xor(ss, 16, 64);
    ss += __shfl_xor(ss, 32, 64);

    // C layout (HW-verified): col = lane&15, row = (lane>>4)*4 + reg
    const int o0   = lane & 15;
    const int crow = r0 + ((lane >> 4) << 2);
    float* pbase = part + (size_t)s * 25 * nrows;
#pragma unroll
    for (int i = 0; i < 4; ++i)
        pbase[(size_t)o0 * nrows + crow + i] = acc0[i];
    if (o0 < NOUTS - 16) {                 // cols 16..23 from tile 1
#pragma unroll
        for (int i = 0; i < 4; ++i)
            pbase[(size_t)(o0 + 16) * nrows + crow + i] = acc1[i];
    }
    if (lane < 16)                         // slot 24 = sumsq, lane == row
        pbase[(size_t)24 * nrows + r0 + lane] = ss;
}

// K2: one wave per row (round-6: thread-per-row at 64 waves total was
// latency-bound). Lane (o = lane&31, g = lane>>5) sums half the slices ->
// shfl_xor(32) fold -> 25 shfl broadcasts -> all lanes run the 4x4 Sinkhorn
// redundantly in registers; lanes 0..15 write C coalesced.
__global__ void sinkhorn_wave_kernel(const float* __restrict__ part,
                                     const float* __restrict__ alpha,
                                     const float* __restrict__ beta,
                                     const int* __restrict__ it_ptr,
                                     float* __restrict__ Cbuf, int nrows, int nslices)
{
    const int lane = threadIdx.x & 63;
    const int row  = blockIdx.x * 4 + (threadIdx.x >> 6);
    if (row >= nrows) return;

    const int o = lane & 31;               // output slot, active for o < 25
    const int g = lane >> 5;               // slice-half 0/1
    float acc = 0.0f;
    if (o < 25) {
#pragma unroll 4
        for (int s = g; s < nslices; s += 2)
            acc += part[((size_t)s * 25 + o) * nrows + row];
    }
    acc += __shfl_xor(acc, 32, 64);        // fold the two slice-halves

    float H[25];
#pragma unroll
    for (int i = 0; i < 25; ++i) H[i] = __shfl(acc, i, 64);   // lane i holds H[i]

    const float r_ = sqrtf((float)NC / H[24]);       // 1/r
    const float a0 = alpha[0], a1 = alpha[1], a2 = alpha[2];

    float Hpre[4], Hpost[4], M[16];
#pragma unroll
    for (int n = 0; n < 4; ++n) {
        const float x = r_ * H[n] * a0 + beta[n];
        Hpre[n] = __builtin_amdgcn_rcpf(1.0f + __expf(-x));
        const float y = r_ * H[4 + n] * a1 + beta[4 + n];
        Hpost[n] = 2.0f * __builtin_amdgcn_rcpf(1.0f + __expf(-y));
    }
#pragma unroll
    for (int k = 0; k < 16; ++k)
        M[k] = __expf(r_ * H[8 + k] * a2 + beta[8 + k]);

    float u[4] = {1.f, 1.f, 1.f, 1.f}, vv[4] = {1.f, 1.f, 1.f, 1.f};
    int iters = *it_ptr;
    if (iters < 0 || iters > 10000) {                // robustness if scalar arrives float-encoded
        const float f = __int_as_float(iters);
        iters = (f >= 0.0f && f < 10000.0f) ? (int)f : 10;
    }
    for (int it = 0; it < iters; ++it) {
#pragma unroll
        for (int i = 0; i < 4; ++i)
            u[i] = __builtin_amdgcn_rcpf(
                M[4*i+0]*vv[0] + M[4*i+1]*vv[1] + M[4*i+2]*vv[2] + M[4*i+3]*vv[3] + 1e-8f);
#pragma unroll
        for (int j2 = 0; j2 < 4; ++j2)
            vv[j2] = __builtin_amdgcn_rcpf(
                M[j2]*u[0] + M[4+j2]*u[1] + M[8+j2]*u[2] + M[12+j2]*u[3] + 1e-8f);
    }

    if (lane < 16) {                       // C[m][n] = Hpost[m]*Hpre[n] + P[m][n]
        const int m = lane >> 2, n = lane & 3;
        Cbuf[(size_t)row * 16 + lane] = Hpost[m] * Hpre[n] + u[m] * M[lane] * vv[n];
    }
}

// K3: pure streaming mix: out[m,d] = sum_n C[m][n] * h[n,d]. One block per row.
__global__ __launch_bounds__(256, 8) void mix_kernel(
    const float* __restrict__ h, const float* __restrict__ Cbuf,
    float* __restrict__ out)
{
    const int row = blockIdx.x;
    const float* cr = Cbuf + (size_t)row * 16;
    float C[16];
#pragma unroll
    for (int k = 0; k < 16; ++k) C[k] = cr[k];       // wave-uniform -> scalar loads

    const float* hr = h + (size_t)row * NC;
    float* orow = out + (size_t)row * NC;
#pragma unroll
    for (int t = 0; t < 2; ++t) {
        const int d0 = t * 1024 + (threadIdx.x << 2);
        float4 hn[4];
#pragma unroll
        for (int n = 0; n < 4; ++n)
            hn[n] = *reinterpret_cast<const float4*>(hr + n * D_ + d0);
#pragma unroll
        for (int m = 0; m < 4; ++m) {
            float4 o4;
            o4.x = C[4*m+0]*hn[0].x + C[4*m+1]*hn[1].x + C[4*m+2]*hn[2].x + C[4*m+3]*hn[3].x;
            o4.y = C[4*m+0]*hn[0].y + C[4*m+1]*hn[1].y + C[4*m+2]*hn[2].y + C[4*m+3]*hn[3].y;
            o4.z = C[4*m+0]*hn[0].z + C[4*m+1]*hn[1].z + C[4*m+2]*hn[2].z + C[4*m+3]*hn[3].z;
            o4.w = C[4*m+0]*hn[0].w + C[4*m+1]*hn[1].w + C[4*m+2]*hn[2].w + C[4*m+3]*hn[3].w;
            *reinterpret_cast<float4*>(orow + m * D_ + d0) = o4;
        }
    }
}

// ======================= fallback (round-2, known-passing) =======================

__global__ void prep_w_kernel(const float* __restrict__ w, float* __restrict__ wp) {
    int idx = blockIdx.x * blockDim.x + threadIdx.x;
    if (idx >= NOUTS * NC) return;
    int o = idx / NC;
    int c = idx - o * NC;
    wp[o * WPAD + c] = w[c * NOUTS + o];
}

__global__ __launch_bounds__(256, 4) void fused_kernel(
    const float* __restrict__ h, const float* __restrict__ gamma,
    const float* __restrict__ wp, const float* __restrict__ alpha,
    const float* __restrict__ beta, const int* __restrict__ it_ptr,
    float* __restrict__ out, int nrows)
{
    const int wave = threadIdx.x >> 6;
    const int lane = threadIdx.x & 63;
    const int row  = (blockIdx.x << 2) | wave;
    if (row >= nrows) return;
    const float* hrow = h + (size_t)row * NC;

    float acc[NOUTS];
#pragma unroll
    for (int o = 0; o < NOUTS; ++o) acc[o] = 0.0f;
    float sumsq = 0.0f;
    const int base = lane << 2;
#pragma unroll 2
    for (int j = 0; j < 32; ++j) {
        const int c0 = base + (j << 8);
        const float4 h4 = *reinterpret_cast<const float4*>(hrow + c0);
        const float4 g4 = *reinterpret_cast<const float4*>(gamma + c0);
        sumsq += h4.x*h4.x + h4.y*h4.y + h4.z*h4.z + h4.w*h4.w;
        const float v0 = h4.x*g4.x, v1 = h4.y*g4.y, v2 = h4.z*g4.z, v3 = h4.w*g4.w;
#pragma unroll
        for (int o = 0; o < NOUTS; ++o) {
            const float4 w4 = *reinterpret_cast<const float4*>(wp + o * WPAD + c0);
            acc[o] += v0*w4.x + v1*w4.y + v2*w4.z + v3*w4.w;
        }
    }
#pragma unroll
    for (int m = 1; m < 64; m <<= 1) {
        sumsq += __shfl_xor(sumsq, m, 64);
#pragma unroll
        for (int o = 0; o < NOUTS; ++o) acc[o] += __shfl_xor(acc[o], m, 64);
    }
    const float r_ = sqrtf((float)NC / sumsq);
    const float a0 = alpha[0], a1 = alpha[1], a2 = alpha[2];
    float Hpre[4], Hpost[4], M[16];
#pragma unroll
    for (int n = 0; n < 4; ++n) {
        const float x = r_ * acc[n] * a0 + beta[n];
        Hpre[n] = __builtin_amdgcn_rcpf(1.0f + __expf(-x));
        const float y = r_ * acc[4 + n] * a1 + beta[4 + n];
        Hpost[n] = 2.0f * __builtin_amdgcn_rcpf(1.0f + __expf(-y));
    }
#pragma unroll
    for (int k = 0; k < 16; ++k)
        M[k] = __expf(r_ * acc[8 + k] * a2 + beta[8 + k]);
    float u[4] = {1.f,1.f,1.f,1.f}, v[4] = {1.f,1.f,1.f,1.f};
    int iters = *it_ptr;
    if (iters < 0 || iters > 10000) {
        const float f = __int_as_float(iters);
        iters = (f >= 0.0f && f < 10000.0f) ? (int)f : 10;
    }
    for (int it = 0; it < iters; ++it) {
#pragma unroll
        for (int i = 0; i < 4; ++i)
            u[i] = __builtin_amdgcn_rcpf(M[4*i+0]*v[0] + M[4*i+1]*v[1] + M[4*i+2]*v[2] + M[4*i+3]*v[3] + 1e-8f);
#pragma unroll
        for (int j2 = 0; j2 < 4; ++j2)
            v[j2] = __builtin_amdgcn_rcpf(M[j2]*u[0] + M[4+j2]*u[1] + M[8+j2]*u[2] + M[12+j2]*u[3] + 1e-8f);
    }
    float P[16];
#pragma unroll
    for (int i = 0; i < 4; ++i)
#pragma unroll
        for (int j2 = 0; j2 < 4; ++j2)
            P[4*i + j2] = u[i] * M[4*i + j2] * v[j2];
    float* orow = out + (size_t)row * NC;
#pragma unroll 2
    for (int t = 0; t < 8; ++t) {
        const int d0 = base + (t << 8);
        float hn[4][4];
#pragma unroll
        for (int n = 0; n < 4; ++n) {
            const float4 x4 = *reinterpret_cast<const float4*>(hrow + n * D_ + d0);
            hn[n][0]=x4.x; hn[n][1]=x4.y; hn[n][2]=x4.z; hn[n][3]=x4.w;
        }
        float hp[4];
#pragma unroll
        for (int k = 0; k < 4; ++k)
            hp[k] = Hpre[0]*hn[0][k] + Hpre[1]*hn[1][k] + Hpre[2]*hn[2][k] + Hpre[3]*hn[3][k];
#pragma unroll
        for (int m = 0; m < 4; ++m) {
            float4 o4;
            o4.x = Hpost[m]*hp[0] + P[4*m+0]*hn[0][0] + P[4*m+1]*hn[1][0] + P[4*m+2]*hn[2][0] + P[4*m+3]*hn[3][0];
            o4.y = Hpost[m]*hp[1] + P[4*m+0]*hn[0][1] + P[4*m+1]*hn[1][1] + P[4*m+2]*hn[2][1] + P[4*m+3]*hn[3][1];
            o4.z = Hpost[m]*hp[2] + P[4*m+0]*hn[0][2] + P[4*m+1]*hn[1][2] + P[4*m+2]*hn[2][2] + P[4*m+3]*hn[3][2];
            o4.w = Hpost[m]*hp[3] + P[4*m+0]*hn[0][3] + P[4*m+1]*hn[1][3] + P[4*m+2]*hn[2][3] + P[4*m+3]*hn[3][3];
            *reinterpret_cast<float4*>(orow + m * D_ + d0) = o4;
        }
    }
}

// ======================= launch =======================

extern "C" void kernel_launch(void* const* d_in, const int* in_sizes, int n_in,
                              void* d_out, int out_size, void* d_ws, size_t ws_size,
                              hipStream_t stream) {
    const float* h     = (const float*)d_in[0];
    const float* gamma = (const float*)d_in[1];
    const float* w     = (const float*)d_in[2];
    const float* alpha = (const float*)d_in[3];
    const float* beta  = (const float*)d_in[4];
    const int*   itp   = (const int*)d_in[5];
    float*       out   = (float*)d_out;

    const int nrows = in_sizes[0] / NC;                       // 4096

    const size_t wb_bytes = (size_t)NB * NC * 2;              // 512 KB bf16 w
    const size_t c_bytes  = (size_t)nrows * 16 * 4;           // 256 KB

    int nslices = 0;
    if ((nrows % 16) == 0) {
        for (int cand = 16; cand >= 4; cand >>= 1) {          // 16 = round-7 measured best (32 regressed)
            const size_t pb = (size_t)cand * 25 * nrows * 4;
            if (ws_size >= wb_bytes + pb + c_bytes) { nslices = cand; break; }
        }
    }

    if (nslices) {
        uint16_t* wb   = (uint16_t*)d_ws;
        float*    part = (float*)((char*)d_ws + wb_bytes);
        float*    Cbuf = (float*)((char*)d_ws + wb_bytes + (size_t)nslices * 25 * nrows * 4);

        const int units = (nrows / 16) * nslices;
        prep_wb_kernel<<<(NB * NC + 255) / 256, 256, 0, stream>>>(w, gamma, wb);
        gemv_mfma_kernel<<<(units + 3) / 4, 256, 0, stream>>>(h, wb, part, nrows, nslices);
        sinkhorn_wave_kernel<<<(nrows + 3) / 4, 256, 0, stream>>>(part, alpha, beta, itp, Cbuf, nrows, nslices);
        mix_kernel<<<nrows, 256, 0, stream>>>(h, Cbuf, out);
    } else {
        float* wp = (float*)d_ws;
        prep_w_kernel<<<(NOUTS * NC + 255) / 256, 256, 0, stream>>>(w, wp);
        fused_kernel<<<(nrows + 3) / 4, 256, 0, stream>>>(h, gamma, wp, alpha, beta, itp, out, nrows);
    }
}

// Round 11
// 117.787 us; speedup vs baseline: 1.0422x; 1.0025x over previous
//
#include <hip/hip_runtime.h>
#include <stdint.h>

// Problem constants: B=2, L=2048, N=4, D=2048
#define NC       8192
#define D_       2048
#define NOUTS    24
#define WPAD     8224        // fallback path: padded row stride for transposed w
#define NB       32          // padded output count for MFMA (24 -> 32, cols 24..31 zero)

typedef __attribute__((ext_vector_type(8))) short short8;
typedef __attribute__((ext_vector_type(4))) float f32x4;

// round-to-nearest-even f32 -> bf16 bits.
// Round-10 post-mortem: __float22bfloat162_rn header path REGRESSED (105.4 ->
// 118.1 us) -- it is not a bare v_cvt_pk_bf16_f32. Reverted to this bit-twiddle
// (round-7 measured best).
__device__ __forceinline__ uint16_t f32_to_bf16_bits(float f) {
    uint32_t u = __builtin_bit_cast(uint32_t, f);
    return (uint16_t)((u + 0x7FFFu + ((u >> 16) & 1u)) >> 16);
}

// ======================= MFMA split path =======================

// prep: wb[o][c] = bf16(gamma[c] * w[c][o]), o in [0,32) with 24..31 zeroed.
__global__ void prep_wb_kernel(const float* __restrict__ w,
                               const float* __restrict__ gamma,
                               uint16_t* __restrict__ wb) {
    int idx = blockIdx.x * blockDim.x + threadIdx.x;
    if (idx >= NB * NC) return;
    int o = idx / NC;
    int c = idx - o * NC;            // consecutive threads -> consecutive c
    float v = (o < NOUTS) ? gamma[c] * w[c * NOUTS + o] : 0.0f;
    wb[o * NC + c] = f32_to_bf16_bits(v);
}

// K1: [16 rows x 24 outs] per wave via mfma_f32_16x16x32_bf16 (two 16-col tiles).
// Geometry: nslices=16, launch_bounds(256,4) -- round-7 measured best (nslices=32
// and no-bounds both regressed; cap 128 > ~100 demand, no spill).
// Round-11 change: k-loop unroll 4 -> 8. HBM MLP accounting: only h-loads are
// HBM (wb is L1/L2-hot); unroll-4 kept just 128B/wave of h in flight (2KB/CU vs
// ~9KB needed). unroll-8 lets the scheduler batch ~2x h-loads within the VGPR cap.
__global__ __launch_bounds__(256, 4) void gemv_mfma_kernel(
    const float* __restrict__ h, const uint16_t* __restrict__ wb,
    float* __restrict__ part, int nrows, int nslices)
{
    const int lane = threadIdx.x & 63;
    const int unit = blockIdx.x * 4 + (threadIdx.x >> 6);
    const int nrg  = nrows >> 4;
    const int rg   = unit % nrg;           // consecutive units share slice s -> wb L1/L2 reuse
    const int s    = unit / nrg;
    if (s >= nslices) return;
    const int r0 = rg * 16;
    const int kw = NC / nslices;           // k-extent per slice (multiple of 32)
    const int k0 = s * kw;

    const int arow = lane & 15;
    const int kgrp = (lane >> 4) << 3;     // 0,8,16,24
    const float*    hA  = h  + (size_t)(r0 + arow) * NC + k0 + kgrp;
    const uint16_t* wB0 = wb + (size_t)arow        * NC + k0 + kgrp;
    const uint16_t* wB1 = wb + (size_t)(arow + 16) * NC + k0 + kgrp;

    f32x4 acc0 = {0.f, 0.f, 0.f, 0.f};
    f32x4 acc1 = {0.f, 0.f, 0.f, 0.f};
    float ss = 0.0f;

#pragma unroll 8
    for (int k = 0; k < kw; k += 32) {
        const float4 a_lo = *reinterpret_cast<const float4*>(hA + k);
        const float4 a_hi = *reinterpret_cast<const float4*>(hA + k + 4);
        const short8 b0 = *reinterpret_cast<const short8*>(wB0 + k);
        const short8 b1 = *reinterpret_cast<const short8*>(wB1 + k);

        ss += a_lo.x*a_lo.x + a_lo.y*a_lo.y + a_lo.z*a_lo.z + a_lo.w*a_lo.w
            + a_hi.x*a_hi.x + a_hi.y*a_hi.y + a_hi.z*a_hi.z + a_hi.w*a_hi.w;

        short8 av;
        av[0] = (short)f32_to_bf16_bits(a_lo.x);
        av[1] = (short)f32_to_bf16_bits(a_lo.y);
        av[2] = (short)f32_to_bf16_bits(a_lo.z);
        av[3] = (short)f32_to_bf16_bits(a_lo.w);
        av[4] = (short)f32_to_bf16_bits(a_hi.x);
        av[5] = (short)f32_to_bf16_bits(a_hi.y);
        av[6] = (short)f32_to_bf16_bits(a_hi.z);
        av[7] = (short)f32_to_bf16_bits(a_hi.w);

        acc0 = __builtin_amdgcn_mfma_f32_16x16x32_bf16(av, b0, acc0, 0, 0, 0);
        acc1 = __builtin_amdgcn_mfma_f32_16x16x32_bf16(av, b1, acc1, 0, 0, 0);
    }

    // sumsq: combine the 4 lane-groups holding the same row
    ss += __shfl_xor(ss, 16, 64);
    ss += __shfl_xor(ss, 32, 64);

    // C layout (HW-verified): col = lane&15, row = (lane>>4)*4 + reg
    const int o0   = lane & 15;
    const int crow = r0 + ((lane >> 4) << 2);
    float* pbase = part + (size_t)s * 25 * nrows;
#pragma unroll
    for (int i = 0; i < 4; ++i)
        pbase[(size_t)o0 * nrows + crow + i] = acc0[i];
    if (o0 < NOUTS - 16) {                 // cols 16..23 from tile 1
#pragma unroll
        for (int i = 0; i < 4; ++i)
            pbase[(size_t)(o0 + 16) * nrows + crow + i] = acc1[i];
    }
    if (lane < 16)                         // slot 24 = sumsq, lane == row
        pbase[(size_t)24 * nrows + r0 + lane] = ss;
}

// K2: one wave per row (round-6: thread-per-row at 64 waves total was
// latency-bound). Lane (o = lane&31, g = lane>>5) sums half the slices ->
// shfl_xor(32) fold -> 25 shfl broadcasts -> all lanes run the 4x4 Sinkhorn
// redundantly in registers; lanes 0..15 write C coalesced.
__global__ void sinkhorn_wave_kernel(const float* __restrict__ part,
                                     const float* __restrict__ alpha,
                                     const float* __restrict__ beta,
                                     const int* __restrict__ it_ptr,
                                     float* __restrict__ Cbuf, int nrows, int nslices)
{
    const int lane = threadIdx.x & 63;
    const int row  = blockIdx.x * 4 + (threadIdx.x >> 6);
    if (row >= nrows) return;

    const int o = lane & 31;               // output slot, active for o < 25
    const int g = lane >> 5;               // slice-half 0/1
    float acc = 0.0f;
    if (o < 25) {
#pragma unroll 4
        for (int s = g; s < nslices; s += 2)
            acc += part[((size_t)s * 25 + o) * nrows + row];
    }
    acc += __shfl_xor(acc, 32, 64);        // fold the two slice-halves

    float H[25];
#pragma unroll
    for (int i = 0; i < 25; ++i) H[i] = __shfl(acc, i, 64);   // lane i holds H[i]

    const float r_ = sqrtf((float)NC / H[24]);       // 1/r
    const float a0 = alpha[0], a1 = alpha[1], a2 = alpha[2];

    float Hpre[4], Hpost[4], M[16];
#pragma unroll
    for (int n = 0; n < 4; ++n) {
        const float x = r_ * H[n] * a0 + beta[n];
        Hpre[n] = __builtin_amdgcn_rcpf(1.0f + __expf(-x));
        const float y = r_ * H[4 + n] * a1 + beta[4 + n];
        Hpost[n] = 2.0f * __builtin_amdgcn_rcpf(1.0f + __expf(-y));
    }
#pragma unroll
    for (int k = 0; k < 16; ++k)
        M[k] = __expf(r_ * H[8 + k] * a2 + beta[8 + k]);

    float u[4] = {1.f, 1.f, 1.f, 1.f}, vv[4] = {1.f, 1.f, 1.f, 1.f};
    int iters = *it_ptr;
    if (iters < 0 || iters > 10000) {                // robustness if scalar arrives float-encoded
        const float f = __int_as_float(iters);
        iters = (f >= 0.0f && f < 10000.0f) ? (int)f : 10;
    }
    for (int it = 0; it < iters; ++it) {
#pragma unroll
        for (int i = 0; i < 4; ++i)
            u[i] = __builtin_amdgcn_rcpf(
                M[4*i+0]*vv[0] + M[4*i+1]*vv[1] + M[4*i+2]*vv[2] + M[4*i+3]*vv[3] + 1e-8f);
#pragma unroll
        for (int j2 = 0; j2 < 4; ++j2)
            vv[j2] = __builtin_amdgcn_rcpf(
                M[j2]*u[0] + M[4+j2]*u[1] + M[8+j2]*u[2] + M[12+j2]*u[3] + 1e-8f);
    }

    if (lane < 16) {                       // C[m][n] = Hpost[m]*Hpre[n] + P[m][n]
        const int m = lane >> 2, n = lane & 3;
        Cbuf[(size_t)row * 16 + lane] = Hpost[m] * Hpre[n] + u[m] * M[lane] * vv[n];
    }
}

// K3: pure streaming mix: out[m,d] = sum_n C[m][n] * h[n,d]. One block per row.
__global__ __launch_bounds__(256, 8) void mix_kernel(
    const float* __restrict__ h, const float* __restrict__ Cbuf,
    float* __restrict__ out)
{
    const int row = blockIdx.x;
    const float* cr = Cbuf + (size_t)row * 16;
    float C[16];
#pragma unroll
    for (int k = 0; k < 16; ++k) C[k] = cr[k];       // wave-uniform -> scalar loads

    const float* hr = h + (size_t)row * NC;
    float* orow = out + (size_t)row * NC;
#pragma unroll
    for (int t = 0; t < 2; ++t) {
        const int d0 = t * 1024 + (threadIdx.x << 2);
        float4 hn[4];
#pragma unroll
        for (int n = 0; n < 4; ++n)
            hn[n] = *reinterpret_cast<const float4*>(hr + n * D_ + d0);
#pragma unroll
        for (int m = 0; m < 4; ++m) {
            float4 o4;
            o4.x = C[4*m+0]*hn[0].x + C[4*m+1]*hn[1].x + C[4*m+2]*hn[2].x + C[4*m+3]*hn[3].x;
            o4.y = C[4*m+0]*hn[0].y + C[4*m+1]*hn[1].y + C[4*m+2]*hn[2].y + C[4*m+3]*hn[3].y;
            o4.z = C[4*m+0]*hn[0].z + C[4*m+1]*hn[1].z + C[4*m+2]*hn[2].z + C[4*m+3]*hn[3].z;
            o4.w = C[4*m+0]*hn[0].w + C[4*m+1]*hn[1].w + C[4*m+2]*hn[2].w + C[4*m+3]*hn[3].w;
            *reinterpret_cast<float4*>(orow + m * D_ + d0) = o4;
        }
    }
}

// ======================= fallback (round-2, known-passing) =======================

__global__ void prep_w_kernel(const float* __restrict__ w, float* __restrict__ wp) {
    int idx = blockIdx.x * blockDim.x + threadIdx.x;
    if (idx >= NOUTS * NC) return;
    int o = idx / NC;
    int c = idx - o * NC;
    wp[o * WPAD + c] = w[c * NOUTS + o];
}

__global__ __launch_bounds__(256, 4) void fused_kernel(
    const float* __restrict__ h, const float* __restrict__ gamma,
    const float* __restrict__ wp, const float* __restrict__ alpha,
    const float* __restrict__ beta, const int* __restrict__ it_ptr,
    float* __restrict__ out, int nrows)
{
    const int wave = threadIdx.x >> 6;
    const int lane = threadIdx.x & 63;
    const int row  = (blockIdx.x << 2) | wave;
    if (row >= nrows) return;
    const float* hrow = h + (size_t)row * NC;

    float acc[NOUTS];
#pragma unroll
    for (int o = 0; o < NOUTS; ++o) acc[o] = 0.0f;
    float sumsq = 0.0f;
    const int base = lane << 2;
#pragma unroll 2
    for (int j = 0; j < 32; ++j) {
        const int c0 = base + (j << 8);
        const float4 h4 = *reinterpret_cast<const float4*>(hrow + c0);
        const float4 g4 = *reinterpret_cast<const float4*>(gamma + c0);
        sumsq += h4.x*h4.x + h4.y*h4.y + h4.z*h4.z + h4.w*h4.w;
        const float v0 = h4.x*g4.x, v1 = h4.y*g4.y, v2 = h4.z*g4.z, v3 = h4.w*g4.w;
#pragma unroll
        for (int o = 0; o < NOUTS; ++o) {
            const float4 w4 = *reinterpret_cast<const float4*>(wp + o * WPAD + c0);
            acc[o] += v0*w4.x + v1*w4.y + v2*w4.z + v3*w4.w;
        }
    }
#pragma unroll
    for (int m = 1; m < 64; m <<= 1) {
        sumsq += __shfl_xor(sumsq, m, 64);
#pragma unroll
        for (int o = 0; o < NOUTS; ++o) acc[o] += __shfl_xor(acc[o], m, 64);
    }
    const float r_ = sqrtf((float)NC / sumsq);
    const float a0 = alpha[0], a1 = alpha[1], a2 = alpha[2];
    float Hpre[4], Hpost[4], M[16];
#pragma unroll
    for (int n = 0; n < 4; ++n) {
        const float x = r_ * acc[n] * a0 + beta[n];
        Hpre[n] = __builtin_amdgcn_rcpf(1.0f + __expf(-x));
        const float y = r_ * acc[4 + n] * a1 + beta[4 + n];
        Hpost[n] = 2.0f * __builtin_amdgcn_rcpf(1.0f + __expf(-y));
    }
#pragma unroll
    for (int k = 0; k < 16; ++k)
        M[k] = __expf(r_ * acc[8 + k] * a2 + beta[8 + k]);
    float u[4] = {1.f,1.f,1.f,1.f}, v[4] = {1.f,1.f,1.f,1.f};
    int iters = *it_ptr;
    if (iters < 0 || iters > 10000) {
        const float f = __int_as_float(iters);
        iters = (f >= 0.0f && f < 10000.0f) ? (int)f : 10;
    }
    for (int it = 0; it < iters; ++it) {
#pragma unroll
        for (int i = 0; i < 4; ++i)
            u[i] = __builtin_amdgcn_rcpf(M[4*i+0]*v[0] + M[4*i+1]*v[1] + M[4*i+2]*v[2] + M[4*i+3]*v[3] + 1e-8f);
#pragma unroll
        for (int j2 = 0; j2 < 4; ++j2)
            v[j2] = __builtin_amdgcn_rcpf(M[j2]*u[0] + M[4+j2]*u[1] + M[8+j2]*u[2] + M[12+j2]*u[3] + 1e-8f);
    }
    float P[16];
#pragma unroll
    for (int i = 0; i < 4; ++i)
#pragma unroll
        for (int j2 = 0; j2 < 4; ++j2)
            P[4*i + j2] = u[i] * M[4*i + j2] * v[j2];
    float* orow = out + (size_t)row * NC;
#pragma unroll 2
    for (int t = 0; t < 8; ++t) {
        const int d0 = base + (t << 8);
        float hn[4][4];
#pragma unroll
        for (int n = 0; n < 4; ++n) {
            const float4 x4 = *reinterpret_cast<const float4*>(hrow + n * D_ + d0);
            hn[n][0]=x4.x; hn[n][1]=x4.y; hn[n][2]=x4.z; hn[n][3]=x4.w;
        }
        float hp[4];
#pragma unroll
        for (int k = 0; k < 4; ++k)
            hp[k] = Hpre[0]*hn[0][k] + Hpre[1]*hn[1][k] + Hpre[2]*hn[2][k] + Hpre[3]*hn[3][k];
#pragma unroll
        for (int m = 0; m < 4; ++m) {
            float4 o4;
            o4.x = Hpost[m]*hp[0] + P[4*m+0]*hn[0][0] + P[4*m+1]*hn[1][0] + P[4*m+2]*hn[2][0] + P[4*m+3]*hn[3][0];
            o4.y = Hpost[m]*hp[1] + P[4*m+0]*hn[0][1] + P[4*m+1]*hn[1][1] + P[4*m+2]*hn[2][1] + P[4*m+3]*hn[3][1];
            o4.z = Hpost[m]*hp[2] + P[4*m+0]*hn[0][2] + P[4*m+1]*hn[1][2] + P[4*m+2]*hn[2][2] + P[4*m+3]*hn[3][2];
            o4.w = Hpost[m]*hp[3] + P[4*m+0]*hn[0][3] + P[4*m+1]*hn[1][3] + P[4*m+2]*hn[2][3] + P[4*m+3]*hn[3][3];
            *reinterpret_cast<float4*>(orow + m * D_ + d0) = o4;
        }
    }
}

// ======================= launch =======================

extern "C" void kernel_launch(void* const* d_in, const int* in_sizes, int n_in,
                              void* d_out, int out_size, void* d_ws, size_t ws_size,
                              hipStream_t stream) {
    const float* h     = (const float*)d_in[0];
    const float* gamma = (const float*)d_in[1];
    const float* w     = (const float*)d_in[2];
    const float* alpha = (const float*)d_in[3];
    const float* beta  = (const float*)d_in[4];
    const int*   itp   = (const int*)d_in[5];
    float*       out   = (float*)d_out;

    const int nrows = in_sizes[0] / NC;                       // 4096

    const size_t wb_bytes = (size_t)NB * NC * 2;              // 512 KB bf16 w
    const size_t c_bytes  = (size_t)nrows * 16 * 4;           // 256 KB

    int nslices = 0;
    if ((nrows % 16) == 0) {
        for (int cand = 16; cand >= 4; cand >>= 1) {          // 16 = round-7 measured best (32 regressed)
            const size_t pb = (size_t)cand * 25 * nrows * 4;
            if (ws_size >= wb_bytes + pb + c_bytes) { nslices = cand; break; }
        }
    }

    if (nslices) {
        uint16_t* wb   = (uint16_t*)d_ws;
        float*    part = (float*)((char*)d_ws + wb_bytes);
        float*    Cbuf = (float*)((char*)d_ws + wb_bytes + (size_t)nslices * 25 * nrows * 4);

        const int units = (nrows / 16) * nslices;
        prep_wb_kernel<<<(NB * NC + 255) / 256, 256, 0, stream>>>(w, gamma, wb);
        gemv_mfma_kernel<<<(units + 3) / 4, 256, 0, stream>>>(h, wb, part, nrows, nslices);
        sinkhorn_wave_kernel<<<(nrows + 3) / 4, 256, 0, stream>>>(part, alpha, beta, itp, Cbuf, nrows, nslices);
        mix_kernel<<<nrows, 256, 0, stream>>>(h, Cbuf, out);
    } else {
        float* wp = (float*)d_ws;
        prep_w_kernel<<<(NOUTS * NC + 255) / 256, 256, 0, stream>>>(w, wp);
        fused_kernel<<<(nrows + 3) / 4, 256, 0, stream>>>(h, gamma, wp, alpha, beta, itp, out, nrows);
    }
}

// Round 12
// 99.674 us; speedup vs baseline: 1.2315x; 1.1817x over previous
//
#include <hip/hip_runtime.h>
#include <stdint.h>

// Problem constants: B=2, L=2048, N=4, D=2048
#define NC       8192
#define D_       2048
#define NOUTS    24
#define WPAD     8224        // fallback path: padded row stride for transposed w
#define NB       32          // padded output count for MFMA (24 -> 32, cols 24..31 zero)
#define KW       512         // k-extent per slice at nslices=16 (LDS gemv path)
#define LPAD     520         // KW + 8 halves: row stride 1040B = 260 dwords = 4 mod 32
                             // -> b128 reads spread 2 lanes/bank (free, m136)

typedef __attribute__((ext_vector_type(8))) short short8;
typedef __attribute__((ext_vector_type(4))) float f32x4;

// round-to-nearest-even f32 -> bf16 bits (r10: header cvt_pk path regressed; keep this)
__device__ __forceinline__ uint16_t f32_to_bf16_bits(float f) {
    uint32_t u = __builtin_bit_cast(uint32_t, f);
    return (uint16_t)((u + 0x7FFFu + ((u >> 16) & 1u)) >> 16);
}

// ======================= MFMA split path =======================

// prep: wb[o][c] = bf16(gamma[c] * w[c][o]), o in [0,32) with 24..31 zeroed.
__global__ void prep_wb_kernel(const float* __restrict__ w,
                               const float* __restrict__ gamma,
                               uint16_t* __restrict__ wb) {
    int idx = blockIdx.x * blockDim.x + threadIdx.x;
    if (idx >= NB * NC) return;
    int o = idx / NC;
    int c = idx - o * NC;            // consecutive threads -> consecutive c
    float v = (o < NOUTS) ? gamma[c] * w[c * NOUTS + o] : 0.0f;
    wb[o * NC + c] = f32_to_bf16_bits(v);
}

// K1 (round-12): LDS-staged wb. All 4 waves of a block share slice s (4 | nrg),
// so stage the block's 32KB wb slice into LDS once; the k-loop's vmcnt queue
// then carries ONLY h-loads (pure HBM stream, in-order vmcnt no longer serializes
// h behind L2 wb returns), wb dest VGPRs freed, 4x less wb L2 traffic.
// Geometry pinned at round-7 best: nslices=16, unroll 4, launch_bounds(256,4).
__global__ __launch_bounds__(256, 4) void gemv_mfma_lds_kernel(
    const float* __restrict__ h, const uint16_t* __restrict__ wb,
    float* __restrict__ part, int nrows)
{
    __shared__ __align__(16) uint16_t lwb[32][LPAD];

    const int tid  = threadIdx.x;
    const int lane = tid & 63;
    const int wid  = tid >> 6;
    const int nrg  = nrows >> 4;           // row-groups of 16; nrg % 4 == 0 guaranteed by launcher
    const int s    = (blockIdx.x * 4) / nrg;   // same slice for all 4 waves
    const int k0   = s * KW;

    // ---- stage wb slice -> LDS: 32 rows x 512 halves; thread t covers 64 halves ----
    {
        const int row = tid >> 3;              // 32 rows, 8 threads/row
        const int col = (tid & 7) << 6;        // 64-half (128B) chunks
        const uint16_t* src = wb + (size_t)row * NC + k0 + col;
        uint16_t* dst = &lwb[row][col];
#pragma unroll
        for (int i = 0; i < 8; ++i)            // 8 x 16B = 128B
            *reinterpret_cast<uint4*>(dst + i * 8) =
                *reinterpret_cast<const uint4*>(src + i * 8);
    }
    __syncthreads();

    const int rg   = (blockIdx.x * 4 + wid) % nrg;
    const int r0   = rg * 16;
    const int arow = lane & 15;
    const int kgrp = (lane >> 4) << 3;         // 0,8,16,24
    const float*    hA  = h + (size_t)(r0 + arow) * NC + k0 + kgrp;
    const uint16_t* lB0 = &lwb[arow][kgrp];
    const uint16_t* lB1 = &lwb[arow + 16][kgrp];

    f32x4 acc0 = {0.f, 0.f, 0.f, 0.f};
    f32x4 acc1 = {0.f, 0.f, 0.f, 0.f};
    float ss = 0.0f;

#pragma unroll 4
    for (int k = 0; k < KW; k += 32) {
        const float4 a_lo = *reinterpret_cast<const float4*>(hA + k);
        const float4 a_hi = *reinterpret_cast<const float4*>(hA + k + 4);
        const short8 b0 = *reinterpret_cast<const short8*>(lB0 + k);
        const short8 b1 = *reinterpret_cast<const short8*>(lB1 + k);

        ss += a_lo.x*a_lo.x + a_lo.y*a_lo.y + a_lo.z*a_lo.z + a_lo.w*a_lo.w
            + a_hi.x*a_hi.x + a_hi.y*a_hi.y + a_hi.z*a_hi.z + a_hi.w*a_hi.w;

        short8 av;
        av[0] = (short)f32_to_bf16_bits(a_lo.x);
        av[1] = (short)f32_to_bf16_bits(a_lo.y);
        av[2] = (short)f32_to_bf16_bits(a_lo.z);
        av[3] = (short)f32_to_bf16_bits(a_lo.w);
        av[4] = (short)f32_to_bf16_bits(a_hi.x);
        av[5] = (short)f32_to_bf16_bits(a_hi.y);
        av[6] = (short)f32_to_bf16_bits(a_hi.z);
        av[7] = (short)f32_to_bf16_bits(a_hi.w);

        acc0 = __builtin_amdgcn_mfma_f32_16x16x32_bf16(av, b0, acc0, 0, 0, 0);
        acc1 = __builtin_amdgcn_mfma_f32_16x16x32_bf16(av, b1, acc1, 0, 0, 0);
    }

    // sumsq: combine the 4 lane-groups holding the same row
    ss += __shfl_xor(ss, 16, 64);
    ss += __shfl_xor(ss, 32, 64);

    // C layout (HW-verified): col = lane&15, row = (lane>>4)*4 + reg
    const int o0   = lane & 15;
    const int crow = r0 + ((lane >> 4) << 2);
    float* pbase = part + (size_t)s * 25 * nrows;
#pragma unroll
    for (int i = 0; i < 4; ++i)
        pbase[(size_t)o0 * nrows + crow + i] = acc0[i];
    if (o0 < NOUTS - 16) {                 // cols 16..23 from tile 1
#pragma unroll
        for (int i = 0; i < 4; ++i)
            pbase[(size_t)(o0 + 16) * nrows + crow + i] = acc1[i];
    }
    if (lane < 16)                         // slot 24 = sumsq, lane == row
        pbase[(size_t)24 * nrows + r0 + lane] = ss;
}

// K1 fallback (round-7 form, global wb) for geometries the LDS path can't take.
__global__ __launch_bounds__(256, 4) void gemv_mfma_kernel(
    const float* __restrict__ h, const uint16_t* __restrict__ wb,
    float* __restrict__ part, int nrows, int nslices)
{
    const int lane = threadIdx.x & 63;
    const int unit = blockIdx.x * 4 + (threadIdx.x >> 6);
    const int nrg  = nrows >> 4;
    const int rg   = unit % nrg;
    const int s    = unit / nrg;
    if (s >= nslices) return;
    const int r0 = rg * 16;
    const int kw = NC / nslices;
    const int k0 = s * kw;

    const int arow = lane & 15;
    const int kgrp = (lane >> 4) << 3;
    const float*    hA  = h  + (size_t)(r0 + arow) * NC + k0 + kgrp;
    const uint16_t* wB0 = wb + (size_t)arow        * NC + k0 + kgrp;
    const uint16_t* wB1 = wb + (size_t)(arow + 16) * NC + k0 + kgrp;

    f32x4 acc0 = {0.f, 0.f, 0.f, 0.f};
    f32x4 acc1 = {0.f, 0.f, 0.f, 0.f};
    float ss = 0.0f;

#pragma unroll 4
    for (int k = 0; k < kw; k += 32) {
        const float4 a_lo = *reinterpret_cast<const float4*>(hA + k);
        const float4 a_hi = *reinterpret_cast<const float4*>(hA + k + 4);
        const short8 b0 = *reinterpret_cast<const short8*>(wB0 + k);
        const short8 b1 = *reinterpret_cast<const short8*>(wB1 + k);

        ss += a_lo.x*a_lo.x + a_lo.y*a_lo.y + a_lo.z*a_lo.z + a_lo.w*a_lo.w
            + a_hi.x*a_hi.x + a_hi.y*a_hi.y + a_hi.z*a_hi.z + a_hi.w*a_hi.w;

        short8 av;
        av[0] = (short)f32_to_bf16_bits(a_lo.x);
        av[1] = (short)f32_to_bf16_bits(a_lo.y);
        av[2] = (short)f32_to_bf16_bits(a_lo.z);
        av[3] = (short)f32_to_bf16_bits(a_lo.w);
        av[4] = (short)f32_to_bf16_bits(a_hi.x);
        av[5] = (short)f32_to_bf16_bits(a_hi.y);
        av[6] = (short)f32_to_bf16_bits(a_hi.z);
        av[7] = (short)f32_to_bf16_bits(a_hi.w);

        acc0 = __builtin_amdgcn_mfma_f32_16x16x32_bf16(av, b0, acc0, 0, 0, 0);
        acc1 = __builtin_amdgcn_mfma_f32_16x16x32_bf16(av, b1, acc1, 0, 0, 0);
    }

    ss += __shfl_xor(ss, 16, 64);
    ss += __shfl_xor(ss, 32, 64);

    const int o0   = lane & 15;
    const int crow = r0 + ((lane >> 4) << 2);
    float* pbase = part + (size_t)s * 25 * nrows;
#pragma unroll
    for (int i = 0; i < 4; ++i)
        pbase[(size_t)o0 * nrows + crow + i] = acc0[i];
    if (o0 < NOUTS - 16) {
#pragma unroll
        for (int i = 0; i < 4; ++i)
            pbase[(size_t)(o0 + 16) * nrows + crow + i] = acc1[i];
    }
    if (lane < 16)
        pbase[(size_t)24 * nrows + r0 + lane] = ss;
}

// K2: one wave per row. Lane (o = lane&31, g = lane>>5) sums half the slices ->
// shfl_xor(32) fold -> 25 shfl broadcasts -> all lanes run the 4x4 Sinkhorn
// redundantly in registers; lanes 0..15 write C coalesced.
__global__ void sinkhorn_wave_kernel(const float* __restrict__ part,
                                     const float* __restrict__ alpha,
                                     const float* __restrict__ beta,
                                     const int* __restrict__ it_ptr,
                                     float* __restrict__ Cbuf, int nrows, int nslices)
{
    const int lane = threadIdx.x & 63;
    const int row  = blockIdx.x * 4 + (threadIdx.x >> 6);
    if (row >= nrows) return;

    const int o = lane & 31;               // output slot, active for o < 25
    const int g = lane >> 5;               // slice-half 0/1
    float acc = 0.0f;
    if (o < 25) {
#pragma unroll 4
        for (int s = g; s < nslices; s += 2)
            acc += part[((size_t)s * 25 + o) * nrows + row];
    }
    acc += __shfl_xor(acc, 32, 64);        // fold the two slice-halves

    float H[25];
#pragma unroll
    for (int i = 0; i < 25; ++i) H[i] = __shfl(acc, i, 64);   // lane i holds H[i]

    const float r_ = sqrtf((float)NC / H[24]);       // 1/r
    const float a0 = alpha[0], a1 = alpha[1], a2 = alpha[2];

    float Hpre[4], Hpost[4], M[16];
#pragma unroll
    for (int n = 0; n < 4; ++n) {
        const float x = r_ * H[n] * a0 + beta[n];
        Hpre[n] = __builtin_amdgcn_rcpf(1.0f + __expf(-x));
        const float y = r_ * H[4 + n] * a1 + beta[4 + n];
        Hpost[n] = 2.0f * __builtin_amdgcn_rcpf(1.0f + __expf(-y));
    }
#pragma unroll
    for (int k = 0; k < 16; ++k)
        M[k] = __expf(r_ * H[8 + k] * a2 + beta[8 + k]);

    float u[4] = {1.f, 1.f, 1.f, 1.f}, vv[4] = {1.f, 1.f, 1.f, 1.f};
    int iters = *it_ptr;
    if (iters < 0 || iters > 10000) {                // robustness if scalar arrives float-encoded
        const float f = __int_as_float(iters);
        iters = (f >= 0.0f && f < 10000.0f) ? (int)f : 10;
    }
    for (int it = 0; it < iters; ++it) {
#pragma unroll
        for (int i = 0; i < 4; ++i)
            u[i] = __builtin_amdgcn_rcpf(
                M[4*i+0]*vv[0] + M[4*i+1]*vv[1] + M[4*i+2]*vv[2] + M[4*i+3]*vv[3] + 1e-8f);
#pragma unroll
        for (int j2 = 0; j2 < 4; ++j2)
            vv[j2] = __builtin_amdgcn_rcpf(
                M[j2]*u[0] + M[4+j2]*u[1] + M[8+j2]*u[2] + M[12+j2]*u[3] + 1e-8f);
    }

    if (lane < 16) {                       // C[m][n] = Hpost[m]*Hpre[n] + P[m][n]
        const int m = lane >> 2, n = lane & 3;
        Cbuf[(size_t)row * 16 + lane] = Hpost[m] * Hpre[n] + u[m] * M[lane] * vv[n];
    }
}

// K3: pure streaming mix: out[m,d] = sum_n C[m][n] * h[n,d]. One block per row.
__global__ __launch_bounds__(256, 8) void mix_kernel(
    const float* __restrict__ h, const float* __restrict__ Cbuf,
    float* __restrict__ out)
{
    const int row = blockIdx.x;
    const float* cr = Cbuf + (size_t)row * 16;
    float C[16];
#pragma unroll
    for (int k = 0; k < 16; ++k) C[k] = cr[k];       // wave-uniform -> scalar loads

    const float* hr = h + (size_t)row * NC;
    float* orow = out + (size_t)row * NC;
#pragma unroll
    for (int t = 0; t < 2; ++t) {
        const int d0 = t * 1024 + (threadIdx.x << 2);
        float4 hn[4];
#pragma unroll
        for (int n = 0; n < 4; ++n)
            hn[n] = *reinterpret_cast<const float4*>(hr + n * D_ + d0);
#pragma unroll
        for (int m = 0; m < 4; ++m) {
            float4 o4;
            o4.x = C[4*m+0]*hn[0].x + C[4*m+1]*hn[1].x + C[4*m+2]*hn[2].x + C[4*m+3]*hn[3].x;
            o4.y = C[4*m+0]*hn[0].y + C[4*m+1]*hn[1].y + C[4*m+2]*hn[2].y + C[4*m+3]*hn[3].y;
            o4.z = C[4*m+0]*hn[0].z + C[4*m+1]*hn[1].z + C[4*m+2]*hn[2].z + C[4*m+3]*hn[3].z;
            o4.w = C[4*m+0]*hn[0].w + C[4*m+1]*hn[1].w + C[4*m+2]*hn[2].w + C[4*m+3]*hn[3].w;
            *reinterpret_cast<float4*>(orow + m * D_ + d0) = o4;
        }
    }
}

// ======================= fallback (round-2, known-passing) =======================

__global__ void prep_w_kernel(const float* __restrict__ w, float* __restrict__ wp) {
    int idx = blockIdx.x * blockDim.x + threadIdx.x;
    if (idx >= NOUTS * NC) return;
    int o = idx / NC;
    int c = idx - o * NC;
    wp[o * WPAD + c] = w[c * NOUTS + o];
}

__global__ __launch_bounds__(256, 4) void fused_kernel(
    const float* __restrict__ h, const float* __restrict__ gamma,
    const float* __restrict__ wp, const float* __restrict__ alpha,
    const float* __restrict__ beta, const int* __restrict__ it_ptr,
    float* __restrict__ out, int nrows)
{
    const int wave = threadIdx.x >> 6;
    const int lane = threadIdx.x & 63;
    const int row  = (blockIdx.x << 2) | wave;
    if (row >= nrows) return;
    const float* hrow = h + (size_t)row * NC;

    float acc[NOUTS];
#pragma unroll
    for (int o = 0; o < NOUTS; ++o) acc[o] = 0.0f;
    float sumsq = 0.0f;
    const int base = lane << 2;
#pragma unroll 2
    for (int j = 0; j < 32; ++j) {
        const int c0 = base + (j << 8);
        const float4 h4 = *reinterpret_cast<const float4*>(hrow + c0);
        const float4 g4 = *reinterpret_cast<const float4*>(gamma + c0);
        sumsq += h4.x*h4.x + h4.y*h4.y + h4.z*h4.z + h4.w*h4.w;
        const float v0 = h4.x*g4.x, v1 = h4.y*g4.y, v2 = h4.z*g4.z, v3 = h4.w*g4.w;
#pragma unroll
        for (int o = 0; o < NOUTS; ++o) {
            const float4 w4 = *reinterpret_cast<const float4*>(wp + o * WPAD + c0);
            acc[o] += v0*w4.x + v1*w4.y + v2*w4.z + v3*w4.w;
        }
    }
#pragma unroll
    for (int m = 1; m < 64; m <<= 1) {
        sumsq += __shfl_xor(sumsq, m, 64);
#pragma unroll
        for (int o = 0; o < NOUTS; ++o) acc[o] += __shfl_xor(acc[o], m, 64);
    }
    const float r_ = sqrtf((float)NC / sumsq);
    const float a0 = alpha[0], a1 = alpha[1], a2 = alpha[2];
    float Hpre[4], Hpost[4], M[16];
#pragma unroll
    for (int n = 0; n < 4; ++n) {
        const float x = r_ * acc[n] * a0 + beta[n];
        Hpre[n] = __builtin_amdgcn_rcpf(1.0f + __expf(-x));
        const float y = r_ * acc[4 + n] * a1 + beta[4 + n];
        Hpost[n] = 2.0f * __builtin_amdgcn_rcpf(1.0f + __expf(-y));
    }
#pragma unroll
    for (int k = 0; k < 16; ++k)
        M[k] = __expf(r_ * acc[8 + k] * a2 + beta[8 + k]);
    float u[4] = {1.f,1.f,1.f,1.f}, v[4] = {1.f,1.f,1.f,1.f};
    int iters = *it_ptr;
    if (iters < 0 || iters > 10000) {
        const float f = __int_as_float(iters);
        iters = (f >= 0.0f && f < 10000.0f) ? (int)f : 10;
    }
    for (int it = 0; it < iters; ++it) {
#pragma unroll
        for (int i = 0; i < 4; ++i)
            u[i] = __builtin_amdgcn_rcpf(M[4*i+0]*v[0] + M[4*i+1]*v[1] + M[4*i+2]*v[2] + M[4*i+3]*v[3] + 1e-8f);
#pragma unroll
        for (int j2 = 0; j2 < 4; ++j2)
            v[j2] = __builtin_amdgcn_rcpf(M[j2]*u[0] + M[4+j2]*u[1] + M[8+j2]*u[2] + M[12+j2]*u[3] + 1e-8f);
    }
    float P[16];
#pragma unroll
    for (int i = 0; i < 4; ++i)
#pragma unroll
        for (int j2 = 0; j2 < 4; ++j2)
            P[4*i + j2] = u[i] * M[4*i + j2] * v[j2];
    float* orow = out + (size_t)row * NC;
#pragma unroll 2
    for (int t = 0; t < 8; ++t) {
        const int d0 = base + (t << 8);
        float hn[4][4];
#pragma unroll
        for (int n = 0; n < 4; ++n) {
            const float4 x4 = *reinterpret_cast<const float4*>(hrow + n * D_ + d0);
            hn[n][0]=x4.x; hn[n][1]=x4.y; hn[n][2]=x4.z; hn[n][3]=x4.w;
        }
        float hp[4];
#pragma unroll
        for (int k = 0; k < 4; ++k)
            hp[k] = Hpre[0]*hn[0][k] + Hpre[1]*hn[1][k] + Hpre[2]*hn[2][k] + Hpre[3]*hn[3][k];
#pragma unroll
        for (int m = 0; m < 4; ++m) {
            float4 o4;
            o4.x = Hpost[m]*hp[0] + P[4*m+0]*hn[0][0] + P[4*m+1]*hn[1][0] + P[4*m+2]*hn[2][0] + P[4*m+3]*hn[3][0];
            o4.y = Hpost[m]*hp[1] + P[4*m+0]*hn[0][1] + P[4*m+1]*hn[1][1] + P[4*m+2]*hn[2][1] + P[4*m+3]*hn[3][1];
            o4.z = Hpost[m]*hp[2] + P[4*m+0]*hn[0][2] + P[4*m+1]*hn[1][2] + P[4*m+2]*hn[2][2] + P[4*m+3]*hn[3][2];
            o4.w = Hpost[m]*hp[3] + P[4*m+0]*hn[0][3] + P[4*m+1]*hn[1][3] + P[4*m+2]*hn[2][3] + P[4*m+3]*hn[3][3];
            *reinterpret_cast<float4*>(orow + m * D_ + d0) = o4;
        }
    }
}

// ======================= launch =======================

extern "C" void kernel_launch(void* const* d_in, const int* in_sizes, int n_in,
                              void* d_out, int out_size, void* d_ws, size_t ws_size,
                              hipStream_t stream) {
    const float* h     = (const float*)d_in[0];
    const float* gamma = (const float*)d_in[1];
    const float* w     = (const float*)d_in[2];
    const float* alpha = (const float*)d_in[3];
    const float* beta  = (const float*)d_in[4];
    const int*   itp   = (const int*)d_in[5];
    float*       out   = (float*)d_out;

    const int nrows = in_sizes[0] / NC;                       // 4096

    const size_t wb_bytes = (size_t)NB * NC * 2;              // 512 KB bf16 w
    const size_t c_bytes  = (size_t)nrows * 16 * 4;           // 256 KB

    int nslices = 0;
    if ((nrows % 16) == 0) {
        for (int cand = 16; cand >= 4; cand >>= 1) {          // 16 = round-7 measured best
            const size_t pb = (size_t)cand * 25 * nrows * 4;
            if (ws_size >= wb_bytes + pb + c_bytes) { nslices = cand; break; }
        }
    }

    if (nslices) {
        uint16_t* wb   = (uint16_t*)d_ws;
        float*    part = (float*)((char*)d_ws + wb_bytes);
        float*    Cbuf = (float*)((char*)d_ws + wb_bytes + (size_t)nslices * 25 * nrows * 4);

        prep_wb_kernel<<<(NB * NC + 255) / 256, 256, 0, stream>>>(w, gamma, wb);
        if (nslices == 16 && (nrows % 64) == 0) {
            // LDS path: 4 waves/block share one slice; nrg % 4 == 0 guaranteed.
            const int units = (nrows / 16) * 16;
            gemv_mfma_lds_kernel<<<units / 4, 256, 0, stream>>>(h, wb, part, nrows);
        } else {
            const int units = (nrows / 16) * nslices;
            gemv_mfma_kernel<<<(units + 3) / 4, 256, 0, stream>>>(h, wb, part, nrows, nslices);
        }
        sinkhorn_wave_kernel<<<(nrows + 3) / 4, 256, 0, stream>>>(part, alpha, beta, itp, Cbuf, nrows, nslices);
        mix_kernel<<<nrows, 256, 0, stream>>>(h, Cbuf, out);
    } else {
        float* wp = (float*)d_ws;
        prep_w_kernel<<<(NOUTS * NC + 255) / 256, 256, 0, stream>>>(w, wp);
        fused_kernel<<<(nrows + 3) / 4, 256, 0, stream>>>(h, gamma, wp, alpha, beta, itp, out, nrows);
    }
}

// Round 13
// 98.334 us; speedup vs baseline: 1.2483x; 1.0136x over previous
//
#include <hip/hip_runtime.h>
#include <stdint.h>

// Problem constants: B=2, L=2048, N=4, D=2048
#define NC       8192
#define D_       2048
#define NOUTS    24
#define WPAD     8224        // fallback path: padded row stride for transposed w
#define NB       32          // padded output count for MFMA (24 -> 32, cols 24..31 zero)
#define KW       512         // k-extent per slice at nslices=16 (LDS gemv path)
#define LPAD     520         // KW + 8 halves: row stride 1040B = 260 dwords = 4 mod 32
                             // -> b128 reads spread 2 lanes/bank (free, m136)

typedef __attribute__((ext_vector_type(8))) short short8;
typedef __attribute__((ext_vector_type(4))) float f32x4;

// round-to-nearest-even f32 -> bf16 bits (r10: header cvt_pk path regressed; keep this)
__device__ __forceinline__ uint16_t f32_to_bf16_bits(float f) {
    uint32_t u = __builtin_bit_cast(uint32_t, f);
    return (uint16_t)((u + 0x7FFFu + ((u >> 16) & 1u)) >> 16);
}

// ======================= MFMA split path =======================

// prep: wb[o][c] = bf16(gamma[c] * w[c][o]), o in [0,32) with 24..31 zeroed.
__global__ void prep_wb_kernel(const float* __restrict__ w,
                               const float* __restrict__ gamma,
                               uint16_t* __restrict__ wb) {
    int idx = blockIdx.x * blockDim.x + threadIdx.x;
    if (idx >= NB * NC) return;
    int o = idx / NC;
    int c = idx - o * NC;            // consecutive threads -> consecutive c
    float v = (o < NOUTS) ? gamma[c] * w[c * NOUTS + o] : 0.0f;
    wb[o * NC + c] = f32_to_bf16_bits(v);
}

// K1: LDS-staged wb (round-12: 105.4 -> 99.7, vmcnt-interference theory confirmed).
// Round-13 change: k-loop unroll 4 -> 8. Retry of r11's null under the new
// structure: wb dest VGPRs are freed and vmcnt carries ONLY h -> deeper unroll
// now doubles h-bytes in flight (128 -> 256 B/wave) without queue pollution.
__global__ __launch_bounds__(256, 4) void gemv_mfma_lds_kernel(
    const float* __restrict__ h, const uint16_t* __restrict__ wb,
    float* __restrict__ part, int nrows)
{
    __shared__ __align__(16) uint16_t lwb[32][LPAD];

    const int tid  = threadIdx.x;
    const int lane = tid & 63;
    const int wid  = tid >> 6;
    const int nrg  = nrows >> 4;           // row-groups of 16; nrg % 4 == 0 guaranteed by launcher
    const int s    = (blockIdx.x * 4) / nrg;   // same slice for all 4 waves
    const int k0   = s * KW;

    // ---- stage wb slice -> LDS: 32 rows x 512 halves; thread t covers 64 halves ----
    {
        const int row = tid >> 3;              // 32 rows, 8 threads/row
        const int col = (tid & 7) << 6;        // 64-half (128B) chunks
        const uint16_t* src = wb + (size_t)row * NC + k0 + col;
        uint16_t* dst = &lwb[row][col];
#pragma unroll
        for (int i = 0; i < 8; ++i)            // 8 x 16B = 128B
            *reinterpret_cast<uint4*>(dst + i * 8) =
                *reinterpret_cast<const uint4*>(src + i * 8);
    }
    __syncthreads();

    const int rg   = (blockIdx.x * 4 + wid) % nrg;
    const int r0   = rg * 16;
    const int arow = lane & 15;
    const int kgrp = (lane >> 4) << 3;         // 0,8,16,24
    const float*    hA  = h + (size_t)(r0 + arow) * NC + k0 + kgrp;
    const uint16_t* lB0 = &lwb[arow][kgrp];
    const uint16_t* lB1 = &lwb[arow + 16][kgrp];

    f32x4 acc0 = {0.f, 0.f, 0.f, 0.f};
    f32x4 acc1 = {0.f, 0.f, 0.f, 0.f};
    float ss = 0.0f;

#pragma unroll 8
    for (int k = 0; k < KW; k += 32) {
        const float4 a_lo = *reinterpret_cast<const float4*>(hA + k);
        const float4 a_hi = *reinterpret_cast<const float4*>(hA + k + 4);
        const short8 b0 = *reinterpret_cast<const short8*>(lB0 + k);
        const short8 b1 = *reinterpret_cast<const short8*>(lB1 + k);

        ss += a_lo.x*a_lo.x + a_lo.y*a_lo.y + a_lo.z*a_lo.z + a_lo.w*a_lo.w
            + a_hi.x*a_hi.x + a_hi.y*a_hi.y + a_hi.z*a_hi.z + a_hi.w*a_hi.w;

        short8 av;
        av[0] = (short)f32_to_bf16_bits(a_lo.x);
        av[1] = (short)f32_to_bf16_bits(a_lo.y);
        av[2] = (short)f32_to_bf16_bits(a_lo.z);
        av[3] = (short)f32_to_bf16_bits(a_lo.w);
        av[4] = (short)f32_to_bf16_bits(a_hi.x);
        av[5] = (short)f32_to_bf16_bits(a_hi.y);
        av[6] = (short)f32_to_bf16_bits(a_hi.z);
        av[7] = (short)f32_to_bf16_bits(a_hi.w);

        acc0 = __builtin_amdgcn_mfma_f32_16x16x32_bf16(av, b0, acc0, 0, 0, 0);
        acc1 = __builtin_amdgcn_mfma_f32_16x16x32_bf16(av, b1, acc1, 0, 0, 0);
    }

    // sumsq: combine the 4 lane-groups holding the same row
    ss += __shfl_xor(ss, 16, 64);
    ss += __shfl_xor(ss, 32, 64);

    // C layout (HW-verified): col = lane&15, row = (lane>>4)*4 + reg
    const int o0   = lane & 15;
    const int crow = r0 + ((lane >> 4) << 2);
    float* pbase = part + (size_t)s * 25 * nrows;
#pragma unroll
    for (int i = 0; i < 4; ++i)
        pbase[(size_t)o0 * nrows + crow + i] = acc0[i];
    if (o0 < NOUTS - 16) {                 // cols 16..23 from tile 1
#pragma unroll
        for (int i = 0; i < 4; ++i)
            pbase[(size_t)(o0 + 16) * nrows + crow + i] = acc1[i];
    }
    if (lane < 16)                         // slot 24 = sumsq, lane == row
        pbase[(size_t)24 * nrows + r0 + lane] = ss;
}

// K1 fallback (round-7 form, global wb) for geometries the LDS path can't take.
__global__ __launch_bounds__(256, 4) void gemv_mfma_kernel(
    const float* __restrict__ h, const uint16_t* __restrict__ wb,
    float* __restrict__ part, int nrows, int nslices)
{
    const int lane = threadIdx.x & 63;
    const int unit = blockIdx.x * 4 + (threadIdx.x >> 6);
    const int nrg  = nrows >> 4;
    const int rg   = unit % nrg;
    const int s    = unit / nrg;
    if (s >= nslices) return;
    const int r0 = rg * 16;
    const int kw = NC / nslices;
    const int k0 = s * kw;

    const int arow = lane & 15;
    const int kgrp = (lane >> 4) << 3;
    const float*    hA  = h  + (size_t)(r0 + arow) * NC + k0 + kgrp;
    const uint16_t* wB0 = wb + (size_t)arow        * NC + k0 + kgrp;
    const uint16_t* wB1 = wb + (size_t)(arow + 16) * NC + k0 + kgrp;

    f32x4 acc0 = {0.f, 0.f, 0.f, 0.f};
    f32x4 acc1 = {0.f, 0.f, 0.f, 0.f};
    float ss = 0.0f;

#pragma unroll 4
    for (int k = 0; k < kw; k += 32) {
        const float4 a_lo = *reinterpret_cast<const float4*>(hA + k);
        const float4 a_hi = *reinterpret_cast<const float4*>(hA + k + 4);
        const short8 b0 = *reinterpret_cast<const short8*>(wB0 + k);
        const short8 b1 = *reinterpret_cast<const short8*>(wB1 + k);

        ss += a_lo.x*a_lo.x + a_lo.y*a_lo.y + a_lo.z*a_lo.z + a_lo.w*a_lo.w
            + a_hi.x*a_hi.x + a_hi.y*a_hi.y + a_hi.z*a_hi.z + a_hi.w*a_hi.w;

        short8 av;
        av[0] = (short)f32_to_bf16_bits(a_lo.x);
        av[1] = (short)f32_to_bf16_bits(a_lo.y);
        av[2] = (short)f32_to_bf16_bits(a_lo.z);
        av[3] = (short)f32_to_bf16_bits(a_lo.w);
        av[4] = (short)f32_to_bf16_bits(a_hi.x);
        av[5] = (short)f32_to_bf16_bits(a_hi.y);
        av[6] = (short)f32_to_bf16_bits(a_hi.z);
        av[7] = (short)f32_to_bf16_bits(a_hi.w);

        acc0 = __builtin_amdgcn_mfma_f32_16x16x32_bf16(av, b0, acc0, 0, 0, 0);
        acc1 = __builtin_amdgcn_mfma_f32_16x16x32_bf16(av, b1, acc1, 0, 0, 0);
    }

    ss += __shfl_xor(ss, 16, 64);
    ss += __shfl_xor(ss, 32, 64);

    const int o0   = lane & 15;
    const int crow = r0 + ((lane >> 4) << 2);
    float* pbase = part + (size_t)s * 25 * nrows;
#pragma unroll
    for (int i = 0; i < 4; ++i)
        pbase[(size_t)o0 * nrows + crow + i] = acc0[i];
    if (o0 < NOUTS - 16) {
#pragma unroll
        for (int i = 0; i < 4; ++i)
            pbase[(size_t)(o0 + 16) * nrows + crow + i] = acc1[i];
    }
    if (lane < 16)
        pbase[(size_t)24 * nrows + r0 + lane] = ss;
}

// K2: one wave per row. Lane (o = lane&31, g = lane>>5) sums half the slices ->
// shfl_xor(32) fold -> 25 shfl broadcasts -> all lanes run the 4x4 Sinkhorn
// redundantly in registers; lanes 0..15 write C coalesced.
__global__ void sinkhorn_wave_kernel(const float* __restrict__ part,
                                     const float* __restrict__ alpha,
                                     const float* __restrict__ beta,
                                     const int* __restrict__ it_ptr,
                                     float* __restrict__ Cbuf, int nrows, int nslices)
{
    const int lane = threadIdx.x & 63;
    const int row  = blockIdx.x * 4 + (threadIdx.x >> 6);
    if (row >= nrows) return;

    const int o = lane & 31;               // output slot, active for o < 25
    const int g = lane >> 5;               // slice-half 0/1
    float acc = 0.0f;
    if (o < 25) {
#pragma unroll 4
        for (int s = g; s < nslices; s += 2)
            acc += part[((size_t)s * 25 + o) * nrows + row];
    }
    acc += __shfl_xor(acc, 32, 64);        // fold the two slice-halves

    float H[25];
#pragma unroll
    for (int i = 0; i < 25; ++i) H[i] = __shfl(acc, i, 64);   // lane i holds H[i]

    const float r_ = sqrtf((float)NC / H[24]);       // 1/r
    const float a0 = alpha[0], a1 = alpha[1], a2 = alpha[2];

    float Hpre[4], Hpost[4], M[16];
#pragma unroll
    for (int n = 0; n < 4; ++n) {
        const float x = r_ * H[n] * a0 + beta[n];
        Hpre[n] = __builtin_amdgcn_rcpf(1.0f + __expf(-x));
        const float y = r_ * H[4 + n] * a1 + beta[4 + n];
        Hpost[n] = 2.0f * __builtin_amdgcn_rcpf(1.0f + __expf(-y));
    }
#pragma unroll
    for (int k = 0; k < 16; ++k)
        M[k] = __expf(r_ * H[8 + k] * a2 + beta[8 + k]);

    float u[4] = {1.f, 1.f, 1.f, 1.f}, vv[4] = {1.f, 1.f, 1.f, 1.f};
    int iters = *it_ptr;
    if (iters < 0 || iters > 10000) {                // robustness if scalar arrives float-encoded
        const float f = __int_as_float(iters);
        iters = (f >= 0.0f && f < 10000.0f) ? (int)f : 10;
    }
    for (int it = 0; it < iters; ++it) {
#pragma unroll
        for (int i = 0; i < 4; ++i)
            u[i] = __builtin_amdgcn_rcpf(
                M[4*i+0]*vv[0] + M[4*i+1]*vv[1] + M[4*i+2]*vv[2] + M[4*i+3]*vv[3] + 1e-8f);
#pragma unroll
        for (int j2 = 0; j2 < 4; ++j2)
            vv[j2] = __builtin_amdgcn_rcpf(
                M[j2]*u[0] + M[4+j2]*u[1] + M[8+j2]*u[2] + M[12+j2]*u[3] + 1e-8f);
    }

    if (lane < 16) {                       // C[m][n] = Hpost[m]*Hpre[n] + P[m][n]
        const int m = lane >> 2, n = lane & 3;
        Cbuf[(size_t)row * 16 + lane] = Hpost[m] * Hpre[n] + u[m] * M[lane] * vv[n];
    }
}

// K3: pure streaming mix: out[m,d] = sum_n C[m][n] * h[n,d]. One block per row.
__global__ __launch_bounds__(256, 8) void mix_kernel(
    const float* __restrict__ h, const float* __restrict__ Cbuf,
    float* __restrict__ out)
{
    const int row = blockIdx.x;
    const float* cr = Cbuf + (size_t)row * 16;
    float C[16];
#pragma unroll
    for (int k = 0; k < 16; ++k) C[k] = cr[k];       // wave-uniform -> scalar loads

    const float* hr = h + (size_t)row * NC;
    float* orow = out + (size_t)row * NC;
#pragma unroll
    for (int t = 0; t < 2; ++t) {
        const int d0 = t * 1024 + (threadIdx.x << 2);
        float4 hn[4];
#pragma unroll
        for (int n = 0; n < 4; ++n)
            hn[n] = *reinterpret_cast<const float4*>(hr + n * D_ + d0);
#pragma unroll
        for (int m = 0; m < 4; ++m) {
            float4 o4;
            o4.x = C[4*m+0]*hn[0].x + C[4*m+1]*hn[1].x + C[4*m+2]*hn[2].x + C[4*m+3]*hn[3].x;
            o4.y = C[4*m+0]*hn[0].y + C[4*m+1]*hn[1].y + C[4*m+2]*hn[2].y + C[4*m+3]*hn[3].y;
            o4.z = C[4*m+0]*hn[0].z + C[4*m+1]*hn[1].z + C[4*m+2]*hn[2].z + C[4*m+3]*hn[3].z;
            o4.w = C[4*m+0]*hn[0].w + C[4*m+1]*hn[1].w + C[4*m+2]*hn[2].w + C[4*m+3]*hn[3].w;
            *reinterpret_cast<float4*>(orow + m * D_ + d0) = o4;
        }
    }
}

// ======================= fallback (round-2, known-passing) =======================

__global__ void prep_w_kernel(const float* __restrict__ w, float* __restrict__ wp) {
    int idx = blockIdx.x * blockDim.x + threadIdx.x;
    if (idx >= NOUTS * NC) return;
    int o = idx / NC;
    int c = idx - o * NC;
    wp[o * WPAD + c] = w[c * NOUTS + o];
}

__global__ __launch_bounds__(256, 4) void fused_kernel(
    const float* __restrict__ h, const float* __restrict__ gamma,
    const float* __restrict__ wp, const float* __restrict__ alpha,
    const float* __restrict__ beta, const int* __restrict__ it_ptr,
    float* __restrict__ out, int nrows)
{
    const int wave = threadIdx.x >> 6;
    const int lane = threadIdx.x & 63;
    const int row  = (blockIdx.x << 2) | wave;
    if (row >= nrows) return;
    const float* hrow = h + (size_t)row * NC;

    float acc[NOUTS];
#pragma unroll
    for (int o = 0; o < NOUTS; ++o) acc[o] = 0.0f;
    float sumsq = 0.0f;
    const int base = lane << 2;
#pragma unroll 2
    for (int j = 0; j < 32; ++j) {
        const int c0 = base + (j << 8);
        const float4 h4 = *reinterpret_cast<const float4*>(hrow + c0);
        const float4 g4 = *reinterpret_cast<const float4*>(gamma + c0);
        sumsq += h4.x*h4.x + h4.y*h4.y + h4.z*h4.z + h4.w*h4.w;
        const float v0 = h4.x*g4.x, v1 = h4.y*g4.y, v2 = h4.z*g4.z, v3 = h4.w*g4.w;
#pragma unroll
        for (int o = 0; o < NOUTS; ++o) {
            const float4 w4 = *reinterpret_cast<const float4*>(wp + o * WPAD + c0);
            acc[o] += v0*w4.x + v1*w4.y + v2*w4.z + v3*w4.w;
        }
    }
#pragma unroll
    for (int m = 1; m < 64; m <<= 1) {
        sumsq += __shfl_xor(sumsq, m, 64);
#pragma unroll
        for (int o = 0; o < NOUTS; ++o) acc[o] += __shfl_xor(acc[o], m, 64);
    }
    const float r_ = sqrtf((float)NC / sumsq);
    const float a0 = alpha[0], a1 = alpha[1], a2 = alpha[2];
    float Hpre[4], Hpost[4], M[16];
#pragma unroll
    for (int n = 0; n < 4; ++n) {
        const float x = r_ * acc[n] * a0 + beta[n];
        Hpre[n] = __builtin_amdgcn_rcpf(1.0f + __expf(-x));
        const float y = r_ * acc[4 + n] * a1 + beta[4 + n];
        Hpost[n] = 2.0f * __builtin_amdgcn_rcpf(1.0f + __expf(-y));
    }
#pragma unroll
    for (int k = 0; k < 16; ++k)
        M[k] = __expf(r_ * acc[8 + k] * a2 + beta[8 + k]);
    float u[4] = {1.f,1.f,1.f,1.f}, v[4] = {1.f,1.f,1.f,1.f};
    int iters = *it_ptr;
    if (iters < 0 || iters > 10000) {
        const float f = __int_as_float(iters);
        iters = (f >= 0.0f && f < 10000.0f) ? (int)f : 10;
    }
    for (int it = 0; it < iters; ++it) {
#pragma unroll
        for (int i = 0; i < 4; ++i)
            u[i] = __builtin_amdgcn_rcpf(M[4*i+0]*v[0] + M[4*i+1]*v[1] + M[4*i+2]*v[2] + M[4*i+3]*v[3] + 1e-8f);
#pragma unroll
        for (int j2 = 0; j2 < 4; ++j2)
            v[j2] = __builtin_amdgcn_rcpf(M[j2]*u[0] + M[4+j2]*u[1] + M[8+j2]*u[2] + M[12+j2]*u[3] + 1e-8f);
    }
    float P[16];
#pragma unroll
    for (int i = 0; i < 4; ++i)
#pragma unroll
        for (int j2 = 0; j2 < 4; ++j2)
            P[4*i + j2] = u[i] * M[4*i + j2] * v[j2];
    float* orow = out + (size_t)row * NC;
#pragma unroll 2
    for (int t = 0; t < 8; ++t) {
        const int d0 = base + (t << 8);
        float hn[4][4];
#pragma unroll
        for (int n = 0; n < 4; ++n) {
            const float4 x4 = *reinterpret_cast<const float4*>(hrow + n * D_ + d0);
            hn[n][0]=x4.x; hn[n][1]=x4.y; hn[n][2]=x4.z; hn[n][3]=x4.w;
        }
        float hp[4];
#pragma unroll
        for (int k = 0; k < 4; ++k)
            hp[k] = Hpre[0]*hn[0][k] + Hpre[1]*hn[1][k] + Hpre[2]*hn[2][k] + Hpre[3]*hn[3][k];
#pragma unroll
        for (int m = 0; m < 4; ++m) {
            float4 o4;
            o4.x = Hpost[m]*hp[0] + P[4*m+0]*hn[0][0] + P[4*m+1]*hn[1][0] + P[4*m+2]*hn[2][0] + P[4*m+3]*hn[3][0];
            o4.y = Hpost[m]*hp[1] + P[4*m+0]*hn[0][1] + P[4*m+1]*hn[1][1] + P[4*m+2]*hn[2][1] + P[4*m+3]*hn[3][1];
            o4.z = Hpost[m]*hp[2] + P[4*m+0]*hn[0][2] + P[4*m+1]*hn[1][2] + P[4*m+2]*hn[2][2] + P[4*m+3]*hn[3][2];
            o4.w = Hpost[m]*hp[3] + P[4*m+0]*hn[0][3] + P[4*m+1]*hn[1][3] + P[4*m+2]*hn[2][3] + P[4*m+3]*hn[3][3];
            *reinterpret_cast<float4*>(orow + m * D_ + d0) = o4;
        }
    }
}

// ======================= launch =======================

extern "C" void kernel_launch(void* const* d_in, const int* in_sizes, int n_in,
                              void* d_out, int out_size, void* d_ws, size_t ws_size,
                              hipStream_t stream) {
    const float* h     = (const float*)d_in[0];
    const float* gamma = (const float*)d_in[1];
    const float* w     = (const float*)d_in[2];
    const float* alpha = (const float*)d_in[3];
    const float* beta  = (const float*)d_in[4];
    const int*   itp   = (const int*)d_in[5];
    float*       out   = (float*)d_out;

    const int nrows = in_sizes[0] / NC;                       // 4096

    const size_t wb_bytes = (size_t)NB * NC * 2;              // 512 KB bf16 w
    const size_t c_bytes  = (size_t)nrows * 16 * 4;           // 256 KB

    int nslices = 0;
    if ((nrows % 16) == 0) {
        for (int cand = 16; cand >= 4; cand >>= 1) {          // 16 = measured best
            const size_t pb = (size_t)cand * 25 * nrows * 4;
            if (ws_size >= wb_bytes + pb + c_bytes) { nslices = cand; break; }
        }
    }

    if (nslices) {
        uint16_t* wb   = (uint16_t*)d_ws;
        float*    part = (float*)((char*)d_ws + wb_bytes);
        float*    Cbuf = (float*)((char*)d_ws + wb_bytes + (size_t)nslices * 25 * nrows * 4);

        prep_wb_kernel<<<(NB * NC + 255) / 256, 256, 0, stream>>>(w, gamma, wb);
        if (nslices == 16 && (nrows % 64) == 0) {
            // LDS path: 4 waves/block share one slice; nrg % 4 == 0 guaranteed.
            const int units = (nrows / 16) * 16;
            gemv_mfma_lds_kernel<<<units / 4, 256, 0, stream>>>(h, wb, part, nrows);
        } else {
            const int units = (nrows / 16) * nslices;
            gemv_mfma_kernel<<<(units + 3) / 4, 256, 0, stream>>>(h, wb, part, nrows, nslices);
        }
        sinkhorn_wave_kernel<<<(nrows + 3) / 4, 256, 0, stream>>>(part, alpha, beta, itp, Cbuf, nrows, nslices);
        mix_kernel<<<nrows, 256, 0, stream>>>(h, Cbuf, out);
    } else {
        float* wp = (float*)d_ws;
        prep_w_kernel<<<(NOUTS * NC + 255) / 256, 256, 0, stream>>>(w, wp);
        fused_kernel<<<(nrows + 3) / 4, 256, 0, stream>>>(h, gamma, wp, alpha, beta, itp, out, nrows);
    }
}

// Round 14
// 95.053 us; speedup vs baseline: 1.2914x; 1.0345x over previous
//
#include <hip/hip_runtime.h>
#include <stdint.h>

// Problem constants: B=2, L=2048, N=4, D=2048
#define NC       8192
#define D_       2048
#define NOUTS    24
#define WPAD     8224        // fallback path: padded row stride for transposed w
#define NB       32          // padded output count for MFMA (24 -> 32, cols 24..31 zero)
#define KW       512         // k-extent per slice at nslices=16 (LDS gemv path)
#define LPAD     520         // KW + 8 halves: row stride 1040B = 260 dwords = 4 mod 32

typedef __attribute__((ext_vector_type(8))) short short8;
typedef __attribute__((ext_vector_type(4))) float f32x4;

// round-to-nearest-even f32 -> bf16 bits (r10: header cvt_pk path regressed; keep this)
__device__ __forceinline__ uint16_t f32_to_bf16_bits(float f) {
    uint32_t u = __builtin_bit_cast(uint32_t, f);
    return (uint16_t)((u + 0x7FFFu + ((u >> 16) & 1u)) >> 16);
}

// ======================= MFMA split path =======================

// prep: wb[o][c] = bf16(gamma[c] * w[c][o]), o in [0,32) with 24..31 zeroed.
__global__ void prep_wb_kernel(const float* __restrict__ w,
                               const float* __restrict__ gamma,
                               uint16_t* __restrict__ wb) {
    int idx = blockIdx.x * blockDim.x + threadIdx.x;
    if (idx >= NB * NC) return;
    int o = idx / NC;
    int c = idx - o * NC;            // consecutive threads -> consecutive c
    float v = (o < NOUTS) ? gamma[c] * w[c * NOUTS + o] : 0.0f;
    wb[o * NC + c] = f32_to_bf16_bits(v);
}

// K1: LDS-staged wb (round-12: 105.4 -> 99.7; round-13 unroll-8: 98.3, at
// structural floor for this geometry).
__global__ __launch_bounds__(256, 4) void gemv_mfma_lds_kernel(
    const float* __restrict__ h, const uint16_t* __restrict__ wb,
    float* __restrict__ part, int nrows)
{
    __shared__ __align__(16) uint16_t lwb[32][LPAD];

    const int tid  = threadIdx.x;
    const int lane = tid & 63;
    const int wid  = tid >> 6;
    const int nrg  = nrows >> 4;           // row-groups of 16; nrg % 4 == 0 guaranteed by launcher
    const int s    = (blockIdx.x * 4) / nrg;   // same slice for all 4 waves
    const int k0   = s * KW;

    // ---- stage wb slice -> LDS: 32 rows x 512 halves ----
    {
        const int row = tid >> 3;              // 32 rows, 8 threads/row
        const int col = (tid & 7) << 6;        // 64-half (128B) chunks
        const uint16_t* src = wb + (size_t)row * NC + k0 + col;
        uint16_t* dst = &lwb[row][col];
#pragma unroll
        for (int i = 0; i < 8; ++i)            // 8 x 16B = 128B
            *reinterpret_cast<uint4*>(dst + i * 8) =
                *reinterpret_cast<const uint4*>(src + i * 8);
    }
    __syncthreads();

    const int rg   = (blockIdx.x * 4 + wid) % nrg;
    const int r0   = rg * 16;
    const int arow = lane & 15;
    const int kgrp = (lane >> 4) << 3;         // 0,8,16,24
    const float*    hA  = h + (size_t)(r0 + arow) * NC + k0 + kgrp;
    const uint16_t* lB0 = &lwb[arow][kgrp];
    const uint16_t* lB1 = &lwb[arow + 16][kgrp];

    f32x4 acc0 = {0.f, 0.f, 0.f, 0.f};
    f32x4 acc1 = {0.f, 0.f, 0.f, 0.f};
    float ss = 0.0f;

#pragma unroll 8
    for (int k = 0; k < KW; k += 32) {
        const float4 a_lo = *reinterpret_cast<const float4*>(hA + k);
        const float4 a_hi = *reinterpret_cast<const float4*>(hA + k + 4);
        const short8 b0 = *reinterpret_cast<const short8*>(lB0 + k);
        const short8 b1 = *reinterpret_cast<const short8*>(lB1 + k);

        ss += a_lo.x*a_lo.x + a_lo.y*a_lo.y + a_lo.z*a_lo.z + a_lo.w*a_lo.w
            + a_hi.x*a_hi.x + a_hi.y*a_hi.y + a_hi.z*a_hi.z + a_hi.w*a_hi.w;

        short8 av;
        av[0] = (short)f32_to_bf16_bits(a_lo.x);
        av[1] = (short)f32_to_bf16_bits(a_lo.y);
        av[2] = (short)f32_to_bf16_bits(a_lo.z);
        av[3] = (short)f32_to_bf16_bits(a_lo.w);
        av[4] = (short)f32_to_bf16_bits(a_hi.x);
        av[5] = (short)f32_to_bf16_bits(a_hi.y);
        av[6] = (short)f32_to_bf16_bits(a_hi.z);
        av[7] = (short)f32_to_bf16_bits(a_hi.w);

        acc0 = __builtin_amdgcn_mfma_f32_16x16x32_bf16(av, b0, acc0, 0, 0, 0);
        acc1 = __builtin_amdgcn_mfma_f32_16x16x32_bf16(av, b1, acc1, 0, 0, 0);
    }

    // sumsq: combine the 4 lane-groups holding the same row
    ss += __shfl_xor(ss, 16, 64);
    ss += __shfl_xor(ss, 32, 64);

    // C layout (HW-verified): col = lane&15, row = (lane>>4)*4 + reg
    const int o0   = lane & 15;
    const int crow = r0 + ((lane >> 4) << 2);
    float* pbase = part + (size_t)s * 25 * nrows;
#pragma unroll
    for (int i = 0; i < 4; ++i)
        pbase[(size_t)o0 * nrows + crow + i] = acc0[i];
    if (o0 < NOUTS - 16) {                 // cols 16..23 from tile 1
#pragma unroll
        for (int i = 0; i < 4; ++i)
            pbase[(size_t)(o0 + 16) * nrows + crow + i] = acc1[i];
    }
    if (lane < 16)                         // slot 24 = sumsq, lane == row
        pbase[(size_t)24 * nrows + r0 + lane] = ss;
}

// K1 fallback (global wb) for geometries the LDS path can't take.
__global__ __launch_bounds__(256, 4) void gemv_mfma_kernel(
    const float* __restrict__ h, const uint16_t* __restrict__ wb,
    float* __restrict__ part, int nrows, int nslices)
{
    const int lane = threadIdx.x & 63;
    const int unit = blockIdx.x * 4 + (threadIdx.x >> 6);
    const int nrg  = nrows >> 4;
    const int rg   = unit % nrg;
    const int s    = unit / nrg;
    if (s >= nslices) return;
    const int r0 = rg * 16;
    const int kw = NC / nslices;
    const int k0 = s * kw;

    const int arow = lane & 15;
    const int kgrp = (lane >> 4) << 3;
    const float*    hA  = h  + (size_t)(r0 + arow) * NC + k0 + kgrp;
    const uint16_t* wB0 = wb + (size_t)arow        * NC + k0 + kgrp;
    const uint16_t* wB1 = wb + (size_t)(arow + 16) * NC + k0 + kgrp;

    f32x4 acc0 = {0.f, 0.f, 0.f, 0.f};
    f32x4 acc1 = {0.f, 0.f, 0.f, 0.f};
    float ss = 0.0f;

#pragma unroll 4
    for (int k = 0; k < kw; k += 32) {
        const float4 a_lo = *reinterpret_cast<const float4*>(hA + k);
        const float4 a_hi = *reinterpret_cast<const float4*>(hA + k + 4);
        const short8 b0 = *reinterpret_cast<const short8*>(wB0 + k);
        const short8 b1 = *reinterpret_cast<const short8*>(wB1 + k);

        ss += a_lo.x*a_lo.x + a_lo.y*a_lo.y + a_lo.z*a_lo.z + a_lo.w*a_lo.w
            + a_hi.x*a_hi.x + a_hi.y*a_hi.y + a_hi.z*a_hi.z + a_hi.w*a_hi.w;

        short8 av;
        av[0] = (short)f32_to_bf16_bits(a_lo.x);
        av[1] = (short)f32_to_bf16_bits(a_lo.y);
        av[2] = (short)f32_to_bf16_bits(a_lo.z);
        av[3] = (short)f32_to_bf16_bits(a_lo.w);
        av[4] = (short)f32_to_bf16_bits(a_hi.x);
        av[5] = (short)f32_to_bf16_bits(a_hi.y);
        av[6] = (short)f32_to_bf16_bits(a_hi.z);
        av[7] = (short)f32_to_bf16_bits(a_hi.w);

        acc0 = __builtin_amdgcn_mfma_f32_16x16x32_bf16(av, b0, acc0, 0, 0, 0);
        acc1 = __builtin_amdgcn_mfma_f32_16x16x32_bf16(av, b1, acc1, 0, 0, 0);
    }

    ss += __shfl_xor(ss, 16, 64);
    ss += __shfl_xor(ss, 32, 64);

    const int o0   = lane & 15;
    const int crow = r0 + ((lane >> 4) << 2);
    float* pbase = part + (size_t)s * 25 * nrows;
#pragma unroll
    for (int i = 0; i < 4; ++i)
        pbase[(size_t)o0 * nrows + crow + i] = acc0[i];
    if (o0 < NOUTS - 16) {
#pragma unroll
        for (int i = 0; i < 4; ++i)
            pbase[(size_t)(o0 + 16) * nrows + crow + i] = acc1[i];
    }
    if (lane < 16)
        pbase[(size_t)24 * nrows + r0 + lane] = ss;
}

// K2+K3 fused (round-14): one 256-thread block per row. All threads prefetch
// BOTH h segments into registers (independent of C -> h-read latency hides
// under the Sinkhorn), wave 0 runs slice-reduce + Sinkhorn and drops C[16] in
// LDS, barrier, all 4 waves compute out = C @ h and stream-store. Kills the
// standalone sinkhorn launch + its dependency gap + the Cbuf roundtrip.
// launch_bounds (256,4): peak demand ~100 VGPR (prefetch 32 + sinkhorn ~60) --
// the old mix's (256,8) cap of 64 would spill (round-3/4 lesson).
__global__ __launch_bounds__(256, 4) void sinkmix_kernel(
    const float* __restrict__ h, const float* __restrict__ part,
    const float* __restrict__ alpha, const float* __restrict__ beta,
    const int* __restrict__ it_ptr, float* __restrict__ out,
    int nrows, int nslices)
{
    __shared__ float Cs[16];
    const int row = blockIdx.x;
    const int tid = threadIdx.x;
    const float* hr = h + (size_t)row * NC;

    // ---- prefetch both h segments (8 x float4, 32 VGPRs) ----
    const int d0 = tid << 2;            // segment A: [0, 1024)
    const int d1 = d0 + 1024;           // segment B: [1024, 2048)
    float4 hA[4], hB[4];
#pragma unroll
    for (int n = 0; n < 4; ++n) {
        hA[n] = *reinterpret_cast<const float4*>(hr + n * D_ + d0);
        hB[n] = *reinterpret_cast<const float4*>(hr + n * D_ + d1);
    }

    // ---- wave 0: slice-reduce + Sinkhorn (identical math to sinkhorn_wave) ----
    if (tid < 64) {
        const int o = tid & 31;            // output slot, active for o < 25
        const int g = tid >> 5;            // slice-half 0/1
        float acc = 0.0f;
        if (o < 25) {
#pragma unroll 4
            for (int s = g; s < nslices; s += 2)
                acc += part[((size_t)s * 25 + o) * nrows + row];
        }
        acc += __shfl_xor(acc, 32, 64);    // fold the two slice-halves

        float H[25];
#pragma unroll
        for (int i = 0; i < 25; ++i) H[i] = __shfl(acc, i, 64);

        const float r_ = sqrtf((float)NC / H[24]);   // 1/r
        const float a0 = alpha[0], a1 = alpha[1], a2 = alpha[2];

        float Hpre[4], Hpost[4], M[16];
#pragma unroll
        for (int n = 0; n < 4; ++n) {
            const float x = r_ * H[n] * a0 + beta[n];
            Hpre[n] = __builtin_amdgcn_rcpf(1.0f + __expf(-x));
            const float y = r_ * H[4 + n] * a1 + beta[4 + n];
            Hpost[n] = 2.0f * __builtin_amdgcn_rcpf(1.0f + __expf(-y));
        }
#pragma unroll
        for (int k = 0; k < 16; ++k)
            M[k] = __expf(r_ * H[8 + k] * a2 + beta[8 + k]);

        float u[4] = {1.f, 1.f, 1.f, 1.f}, vv[4] = {1.f, 1.f, 1.f, 1.f};
        int iters = *it_ptr;
        if (iters < 0 || iters > 10000) {            // robustness: float-encoded scalar
            const float f = __int_as_float(iters);
            iters = (f >= 0.0f && f < 10000.0f) ? (int)f : 10;
        }
        for (int it = 0; it < iters; ++it) {
#pragma unroll
            for (int i = 0; i < 4; ++i)
                u[i] = __builtin_amdgcn_rcpf(
                    M[4*i+0]*vv[0] + M[4*i+1]*vv[1] + M[4*i+2]*vv[2] + M[4*i+3]*vv[3] + 1e-8f);
#pragma unroll
            for (int j2 = 0; j2 < 4; ++j2)
                vv[j2] = __builtin_amdgcn_rcpf(
                    M[j2]*u[0] + M[4+j2]*u[1] + M[8+j2]*u[2] + M[12+j2]*u[3] + 1e-8f);
        }

        if (tid < 16) {                    // C[m][n] = Hpost[m]*Hpre[n] + P[m][n]
            const int m = tid >> 2, n = tid & 3;
            Cs[tid] = Hpost[m] * Hpre[n] + u[m] * M[tid] * vv[n];
        }
    }
    __syncthreads();

    float C[16];
#pragma unroll
    for (int k = 0; k < 16; ++k) C[k] = Cs[k];       // wave-uniform broadcast

    float* orow = out + (size_t)row * NC;
#pragma unroll
    for (int m = 0; m < 4; ++m) {
        float4 oA, oB;
        oA.x = C[4*m+0]*hA[0].x + C[4*m+1]*hA[1].x + C[4*m+2]*hA[2].x + C[4*m+3]*hA[3].x;
        oA.y = C[4*m+0]*hA[0].y + C[4*m+1]*hA[1].y + C[4*m+2]*hA[2].y + C[4*m+3]*hA[3].y;
        oA.z = C[4*m+0]*hA[0].z + C[4*m+1]*hA[1].z + C[4*m+2]*hA[2].z + C[4*m+3]*hA[3].z;
        oA.w = C[4*m+0]*hA[0].w + C[4*m+1]*hA[1].w + C[4*m+2]*hA[2].w + C[4*m+3]*hA[3].w;
        oB.x = C[4*m+0]*hB[0].x + C[4*m+1]*hB[1].x + C[4*m+2]*hB[2].x + C[4*m+3]*hB[3].x;
        oB.y = C[4*m+0]*hB[0].y + C[4*m+1]*hB[1].y + C[4*m+2]*hB[2].y + C[4*m+3]*hB[3].y;
        oB.z = C[4*m+0]*hB[0].z + C[4*m+1]*hB[1].z + C[4*m+2]*hB[2].z + C[4*m+3]*hB[3].z;
        oB.w = C[4*m+0]*hB[0].w + C[4*m+1]*hB[1].w + C[4*m+2]*hB[2].w + C[4*m+3]*hB[3].w;
        *reinterpret_cast<float4*>(orow + m * D_ + d0) = oA;
        *reinterpret_cast<float4*>(orow + m * D_ + d1) = oB;
    }
}

// ======================= fallback (round-2, known-passing) =======================

__global__ void prep_w_kernel(const float* __restrict__ w, float* __restrict__ wp) {
    int idx = blockIdx.x * blockDim.x + threadIdx.x;
    if (idx >= NOUTS * NC) return;
    int o = idx / NC;
    int c = idx - o * NC;
    wp[o * WPAD + c] = w[c * NOUTS + o];
}

__global__ __launch_bounds__(256, 4) void fused_kernel(
    const float* __restrict__ h, const float* __restrict__ gamma,
    const float* __restrict__ wp, const float* __restrict__ alpha,
    const float* __restrict__ beta, const int* __restrict__ it_ptr,
    float* __restrict__ out, int nrows)
{
    const int wave = threadIdx.x >> 6;
    const int lane = threadIdx.x & 63;
    const int row  = (blockIdx.x << 2) | wave;
    if (row >= nrows) return;
    const float* hrow = h + (size_t)row * NC;

    float acc[NOUTS];
#pragma unroll
    for (int o = 0; o < NOUTS; ++o) acc[o] = 0.0f;
    float sumsq = 0.0f;
    const int base = lane << 2;
#pragma unroll 2
    for (int j = 0; j < 32; ++j) {
        const int c0 = base + (j << 8);
        const float4 h4 = *reinterpret_cast<const float4*>(hrow + c0);
        const float4 g4 = *reinterpret_cast<const float4*>(gamma + c0);
        sumsq += h4.x*h4.x + h4.y*h4.y + h4.z*h4.z + h4.w*h4.w;
        const float v0 = h4.x*g4.x, v1 = h4.y*g4.y, v2 = h4.z*g4.z, v3 = h4.w*g4.w;
#pragma unroll
        for (int o = 0; o < NOUTS; ++o) {
            const float4 w4 = *reinterpret_cast<const float4*>(wp + o * WPAD + c0);
            acc[o] += v0*w4.x + v1*w4.y + v2*w4.z + v3*w4.w;
        }
    }
#pragma unroll
    for (int m = 1; m < 64; m <<= 1) {
        sumsq += __shfl_xor(sumsq, m, 64);
#pragma unroll
        for (int o = 0; o < NOUTS; ++o) acc[o] += __shfl_xor(acc[o], m, 64);
    }
    const float r_ = sqrtf((float)NC / sumsq);
    const float a0 = alpha[0], a1 = alpha[1], a2 = alpha[2];
    float Hpre[4], Hpost[4], M[16];
#pragma unroll
    for (int n = 0; n < 4; ++n) {
        const float x = r_ * acc[n] * a0 + beta[n];
        Hpre[n] = __builtin_amdgcn_rcpf(1.0f + __expf(-x));
        const float y = r_ * acc[4 + n] * a1 + beta[4 + n];
        Hpost[n] = 2.0f * __builtin_amdgcn_rcpf(1.0f + __expf(-y));
    }
#pragma unroll
    for (int k = 0; k < 16; ++k)
        M[k] = __expf(r_ * acc[8 + k] * a2 + beta[8 + k]);
    float u[4] = {1.f,1.f,1.f,1.f}, v[4] = {1.f,1.f,1.f,1.f};
    int iters = *it_ptr;
    if (iters < 0 || iters > 10000) {
        const float f = __int_as_float(iters);
        iters = (f >= 0.0f && f < 10000.0f) ? (int)f : 10;
    }
    for (int it = 0; it < iters; ++it) {
#pragma unroll
        for (int i = 0; i < 4; ++i)
            u[i] = __builtin_amdgcn_rcpf(M[4*i+0]*v[0] + M[4*i+1]*v[1] + M[4*i+2]*v[2] + M[4*i+3]*v[3] + 1e-8f);
#pragma unroll
        for (int j2 = 0; j2 < 4; ++j2)
            v[j2] = __builtin_amdgcn_rcpf(M[j2]*u[0] + M[4+j2]*u[1] + M[8+j2]*u[2] + M[12+j2]*u[3] + 1e-8f);
    }
    float P[16];
#pragma unroll
    for (int i = 0; i < 4; ++i)
#pragma unroll
        for (int j2 = 0; j2 < 4; ++j2)
            P[4*i + j2] = u[i] * M[4*i + j2] * v[j2];
    float* orow = out + (size_t)row * NC;
#pragma unroll 2
    for (int t = 0; t < 8; ++t) {
        const int d0 = base + (t << 8);
        float hn[4][4];
#pragma unroll
        for (int n = 0; n < 4; ++n) {
            const float4 x4 = *reinterpret_cast<const float4*>(hrow + n * D_ + d0);
            hn[n][0]=x4.x; hn[n][1]=x4.y; hn[n][2]=x4.z; hn[n][3]=x4.w;
        }
        float hp[4];
#pragma unroll
        for (int k = 0; k < 4; ++k)
            hp[k] = Hpre[0]*hn[0][k] + Hpre[1]*hn[1][k] + Hpre[2]*hn[2][k] + Hpre[3]*hn[3][k];
#pragma unroll
        for (int m = 0; m < 4; ++m) {
            float4 o4;
            o4.x = Hpost[m]*hp[0] + P[4*m+0]*hn[0][0] + P[4*m+1]*hn[1][0] + P[4*m+2]*hn[2][0] + P[4*m+3]*hn[3][0];
            o4.y = Hpost[m]*hp[1] + P[4*m+0]*hn[0][1] + P[4*m+1]*hn[1][1] + P[4*m+2]*hn[2][1] + P[4*m+3]*hn[3][1];
            o4.z = Hpost[m]*hp[2] + P[4*m+0]*hn[0][2] + P[4*m+1]*hn[1][2] + P[4*m+2]*hn[2][2] + P[4*m+3]*hn[3][2];
            o4.w = Hpost[m]*hp[3] + P[4*m+0]*hn[0][3] + P[4*m+1]*hn[1][3] + P[4*m+2]*hn[2][3] + P[4*m+3]*hn[3][3];
            *reinterpret_cast<float4*>(orow + m * D_ + d0) = o4;
        }
    }
}

// ======================= launch =======================

extern "C" void kernel_launch(void* const* d_in, const int* in_sizes, int n_in,
                              void* d_out, int out_size, void* d_ws, size_t ws_size,
                              hipStream_t stream) {
    const float* h     = (const float*)d_in[0];
    const float* gamma = (const float*)d_in[1];
    const float* w     = (const float*)d_in[2];
    const float* alpha = (const float*)d_in[3];
    const float* beta  = (const float*)d_in[4];
    const int*   itp   = (const int*)d_in[5];
    float*       out   = (float*)d_out;

    const int nrows = in_sizes[0] / NC;                       // 4096

    const size_t wb_bytes = (size_t)NB * NC * 2;              // 512 KB bf16 w
    const size_t c_bytes  = (size_t)nrows * 16 * 4;           // 256 KB (slack)

    int nslices = 0;
    if ((nrows % 16) == 0) {
        for (int cand = 16; cand >= 4; cand >>= 1) {          // 16 = measured best
            const size_t pb = (size_t)cand * 25 * nrows * 4;
            if (ws_size >= wb_bytes + pb + c_bytes) { nslices = cand; break; }
        }
    }

    if (nslices) {
        uint16_t* wb   = (uint16_t*)d_ws;
        float*    part = (float*)((char*)d_ws + wb_bytes);

        prep_wb_kernel<<<(NB * NC + 255) / 256, 256, 0, stream>>>(w, gamma, wb);
        if (nslices == 16 && (nrows % 64) == 0) {
            // LDS path: 4 waves/block share one slice; nrg % 4 == 0 guaranteed.
            const int units = (nrows / 16) * 16;
            gemv_mfma_lds_kernel<<<units / 4, 256, 0, stream>>>(h, wb, part, nrows);
        } else {
            const int units = (nrows / 16) * nslices;
            gemv_mfma_kernel<<<(units + 3) / 4, 256, 0, stream>>>(h, wb, part, nrows, nslices);
        }
        sinkmix_kernel<<<nrows, 256, 0, stream>>>(h, part, alpha, beta, itp, out, nrows, nslices);
    } else {
        float* wp = (float*)d_ws;
        prep_w_kernel<<<(NOUTS * NC + 255) / 256, 256, 0, stream>>>(w, wp);
        fused_kernel<<<(nrows + 3) / 4, 256, 0, stream>>>(h, gamma, wp, alpha, beta, itp, out, nrows);
    }
}

// Round 15
// 94.235 us; speedup vs baseline: 1.3026x; 1.0087x over previous
//
#include <hip/hip_runtime.h>
#include <stdint.h>

// Problem constants: B=2, L=2048, N=4, D=2048
#define NC       8192
#define D_       2048
#define NOUTS    24
#define WPAD     8224        // fallback path: padded row stride for transposed w
#define NB       32          // padded output count for MFMA (24 -> 32, cols 24..31 zero)
#define KW       512         // k-extent per slice at nslices=16 (LDS gemv path)
#define LPAD     520         // KW + 8 halves: row stride 1040B = 260 dwords = 4 mod 32

typedef __attribute__((ext_vector_type(8))) short short8;
typedef __attribute__((ext_vector_type(4))) float f32x4;

// round-to-nearest-even f32 -> bf16 bits (r10: header cvt_pk path regressed; keep this)
__device__ __forceinline__ uint16_t f32_to_bf16_bits(float f) {
    uint32_t u = __builtin_bit_cast(uint32_t, f);
    return (uint16_t)((u + 0x7FFFu + ((u >> 16) & 1u)) >> 16);
}

// ======================= MFMA split path =======================

// prep: wb[o][c] = bf16(gamma[c] * w[c][o]), o in [0,32) with 24..31 zeroed.
__global__ void prep_wb_kernel(const float* __restrict__ w,
                               const float* __restrict__ gamma,
                               uint16_t* __restrict__ wb) {
    int idx = blockIdx.x * blockDim.x + threadIdx.x;
    if (idx >= NB * NC) return;
    int o = idx / NC;
    int c = idx - o * NC;            // consecutive threads -> consecutive c
    float v = (o < NOUTS) ? gamma[c] * w[c * NOUTS + o] : 0.0f;
    wb[o * NC + c] = f32_to_bf16_bits(v);
}

// K1: LDS-staged wb (round-12: 105.4 -> 99.7; round-13 unroll-8: 98.3; at
// structural floor for this geometry).
__global__ __launch_bounds__(256, 4) void gemv_mfma_lds_kernel(
    const float* __restrict__ h, const uint16_t* __restrict__ wb,
    float* __restrict__ part, int nrows)
{
    __shared__ __align__(16) uint16_t lwb[32][LPAD];

    const int tid  = threadIdx.x;
    const int lane = tid & 63;
    const int wid  = tid >> 6;
    const int nrg  = nrows >> 4;           // row-groups of 16; nrg % 4 == 0 guaranteed by launcher
    const int s    = (blockIdx.x * 4) / nrg;   // same slice for all 4 waves
    const int k0   = s * KW;

    // ---- stage wb slice -> LDS: 32 rows x 512 halves ----
    {
        const int row = tid >> 3;              // 32 rows, 8 threads/row
        const int col = (tid & 7) << 6;        // 64-half (128B) chunks
        const uint16_t* src = wb + (size_t)row * NC + k0 + col;
        uint16_t* dst = &lwb[row][col];
#pragma unroll
        for (int i = 0; i < 8; ++i)            // 8 x 16B = 128B
            *reinterpret_cast<uint4*>(dst + i * 8) =
                *reinterpret_cast<const uint4*>(src + i * 8);
    }
    __syncthreads();

    const int rg   = (blockIdx.x * 4 + wid) % nrg;
    const int r0   = rg * 16;
    const int arow = lane & 15;
    const int kgrp = (lane >> 4) << 3;         // 0,8,16,24
    const float*    hA  = h + (size_t)(r0 + arow) * NC + k0 + kgrp;
    const uint16_t* lB0 = &lwb[arow][kgrp];
    const uint16_t* lB1 = &lwb[arow + 16][kgrp];

    f32x4 acc0 = {0.f, 0.f, 0.f, 0.f};
    f32x4 acc1 = {0.f, 0.f, 0.f, 0.f};
    float ss = 0.0f;

#pragma unroll 8
    for (int k = 0; k < KW; k += 32) {
        const float4 a_lo = *reinterpret_cast<const float4*>(hA + k);
        const float4 a_hi = *reinterpret_cast<const float4*>(hA + k + 4);
        const short8 b0 = *reinterpret_cast<const short8*>(lB0 + k);
        const short8 b1 = *reinterpret_cast<const short8*>(lB1 + k);

        ss += a_lo.x*a_lo.x + a_lo.y*a_lo.y + a_lo.z*a_lo.z + a_lo.w*a_lo.w
            + a_hi.x*a_hi.x + a_hi.y*a_hi.y + a_hi.z*a_hi.z + a_hi.w*a_hi.w;

        short8 av;
        av[0] = (short)f32_to_bf16_bits(a_lo.x);
        av[1] = (short)f32_to_bf16_bits(a_lo.y);
        av[2] = (short)f32_to_bf16_bits(a_lo.z);
        av[3] = (short)f32_to_bf16_bits(a_lo.w);
        av[4] = (short)f32_to_bf16_bits(a_hi.x);
        av[5] = (short)f32_to_bf16_bits(a_hi.y);
        av[6] = (short)f32_to_bf16_bits(a_hi.z);
        av[7] = (short)f32_to_bf16_bits(a_hi.w);

        acc0 = __builtin_amdgcn_mfma_f32_16x16x32_bf16(av, b0, acc0, 0, 0, 0);
        acc1 = __builtin_amdgcn_mfma_f32_16x16x32_bf16(av, b1, acc1, 0, 0, 0);
    }

    // sumsq: combine the 4 lane-groups holding the same row
    ss += __shfl_xor(ss, 16, 64);
    ss += __shfl_xor(ss, 32, 64);

    // C layout (HW-verified): col = lane&15, row = (lane>>4)*4 + reg
    const int o0   = lane & 15;
    const int crow = r0 + ((lane >> 4) << 2);
    float* pbase = part + (size_t)s * 25 * nrows;
#pragma unroll
    for (int i = 0; i < 4; ++i)
        pbase[(size_t)o0 * nrows + crow + i] = acc0[i];
    if (o0 < NOUTS - 16) {                 // cols 16..23 from tile 1
#pragma unroll
        for (int i = 0; i < 4; ++i)
            pbase[(size_t)(o0 + 16) * nrows + crow + i] = acc1[i];
    }
    if (lane < 16)                         // slot 24 = sumsq, lane == row
        pbase[(size_t)24 * nrows + r0 + lane] = ss;
}

// K1 fallback (global wb) for geometries the LDS path can't take.
__global__ __launch_bounds__(256, 4) void gemv_mfma_kernel(
    const float* __restrict__ h, const uint16_t* __restrict__ wb,
    float* __restrict__ part, int nrows, int nslices)
{
    const int lane = threadIdx.x & 63;
    const int unit = blockIdx.x * 4 + (threadIdx.x >> 6);
    const int nrg  = nrows >> 4;
    const int rg   = unit % nrg;
    const int s    = unit / nrg;
    if (s >= nslices) return;
    const int r0 = rg * 16;
    const int kw = NC / nslices;
    const int k0 = s * kw;

    const int arow = lane & 15;
    const int kgrp = (lane >> 4) << 3;
    const float*    hA  = h  + (size_t)(r0 + arow) * NC + k0 + kgrp;
    const uint16_t* wB0 = wb + (size_t)arow        * NC + k0 + kgrp;
    const uint16_t* wB1 = wb + (size_t)(arow + 16) * NC + k0 + kgrp;

    f32x4 acc0 = {0.f, 0.f, 0.f, 0.f};
    f32x4 acc1 = {0.f, 0.f, 0.f, 0.f};
    float ss = 0.0f;

#pragma unroll 4
    for (int k = 0; k < kw; k += 32) {
        const float4 a_lo = *reinterpret_cast<const float4*>(hA + k);
        const float4 a_hi = *reinterpret_cast<const float4*>(hA + k + 4);
        const short8 b0 = *reinterpret_cast<const short8*>(wB0 + k);
        const short8 b1 = *reinterpret_cast<const short8*>(wB1 + k);

        ss += a_lo.x*a_lo.x + a_lo.y*a_lo.y + a_lo.z*a_lo.z + a_lo.w*a_lo.w
            + a_hi.x*a_hi.x + a_hi.y*a_hi.y + a_hi.z*a_hi.z + a_hi.w*a_hi.w;

        short8 av;
        av[0] = (short)f32_to_bf16_bits(a_lo.x);
        av[1] = (short)f32_to_bf16_bits(a_lo.y);
        av[2] = (short)f32_to_bf16_bits(a_lo.z);
        av[3] = (short)f32_to_bf16_bits(a_lo.w);
        av[4] = (short)f32_to_bf16_bits(a_hi.x);
        av[5] = (short)f32_to_bf16_bits(a_hi.y);
        av[6] = (short)f32_to_bf16_bits(a_hi.z);
        av[7] = (short)f32_to_bf16_bits(a_hi.w);

        acc0 = __builtin_amdgcn_mfma_f32_16x16x32_bf16(av, b0, acc0, 0, 0, 0);
        acc1 = __builtin_amdgcn_mfma_f32_16x16x32_bf16(av, b1, acc1, 0, 0, 0);
    }

    ss += __shfl_xor(ss, 16, 64);
    ss += __shfl_xor(ss, 32, 64);

    const int o0   = lane & 15;
    const int crow = r0 + ((lane >> 4) << 2);
    float* pbase = part + (size_t)s * 25 * nrows;
#pragma unroll
    for (int i = 0; i < 4; ++i)
        pbase[(size_t)o0 * nrows + crow + i] = acc0[i];
    if (o0 < NOUTS - 16) {
#pragma unroll
        for (int i = 0; i < 4; ++i)
            pbase[(size_t)(o0 + 16) * nrows + crow + i] = acc1[i];
    }
    if (lane < 16)
        pbase[(size_t)24 * nrows + r0 + lane] = ss;
}

// K2+K3 fused. Round-15 change: register diet + occupancy bump. Prefetch only
// segment A (16 regs) before the Sinkhorn; segment B loads inline after the
// barrier. Peak demand drops ~100 -> ~86-96 VGPR -> launch_bounds(256,5)
// (cap 102, 5 blocks/CU = +25% TLP to cover the serial sinkhorn phase where
// 3 of 4 waves idle, and deeper streaming overlap).
__global__ __launch_bounds__(256, 5) void sinkmix_kernel(
    const float* __restrict__ h, const float* __restrict__ part,
    const float* __restrict__ alpha, const float* __restrict__ beta,
    const int* __restrict__ it_ptr, float* __restrict__ out,
    int nrows, int nslices)
{
    __shared__ float Cs[16];
    const int row = blockIdx.x;
    const int tid = threadIdx.x;
    const float* hr = h + (size_t)row * NC;

    // ---- prefetch segment A only (4 x float4, 16 VGPRs) ----
    const int d0 = tid << 2;            // segment A: [0, 1024)
    const int d1 = d0 + 1024;           // segment B: [1024, 2048)
    float4 hA[4];
#pragma unroll
    for (int n = 0; n < 4; ++n)
        hA[n] = *reinterpret_cast<const float4*>(hr + n * D_ + d0);

    // ---- wave 0: slice-reduce + Sinkhorn ----
    if (tid < 64) {
        const int o = tid & 31;            // output slot, active for o < 25
        const int g = tid >> 5;            // slice-half 0/1
        float acc = 0.0f;
        if (o < 25) {
#pragma unroll 4
            for (int s = g; s < nslices; s += 2)
                acc += part[((size_t)s * 25 + o) * nrows + row];
        }
        acc += __shfl_xor(acc, 32, 64);    // fold the two slice-halves

        float H[25];
#pragma unroll
        for (int i = 0; i < 25; ++i) H[i] = __shfl(acc, i, 64);

        const float r_ = sqrtf((float)NC / H[24]);   // 1/r
        const float a0 = alpha[0], a1 = alpha[1], a2 = alpha[2];

        float Hpre[4], Hpost[4], M[16];
#pragma unroll
        for (int n = 0; n < 4; ++n) {
            const float x = r_ * H[n] * a0 + beta[n];
            Hpre[n] = __builtin_amdgcn_rcpf(1.0f + __expf(-x));
            const float y = r_ * H[4 + n] * a1 + beta[4 + n];
            Hpost[n] = 2.0f * __builtin_amdgcn_rcpf(1.0f + __expf(-y));
        }
#pragma unroll
        for (int k = 0; k < 16; ++k)
            M[k] = __expf(r_ * H[8 + k] * a2 + beta[8 + k]);

        float u[4] = {1.f, 1.f, 1.f, 1.f}, vv[4] = {1.f, 1.f, 1.f, 1.f};
        int iters = *it_ptr;
        if (iters < 0 || iters > 10000) {            // robustness: float-encoded scalar
            const float f = __int_as_float(iters);
            iters = (f >= 0.0f && f < 10000.0f) ? (int)f : 10;
        }
        for (int it = 0; it < iters; ++it) {
#pragma unroll
            for (int i = 0; i < 4; ++i)
                u[i] = __builtin_amdgcn_rcpf(
                    M[4*i+0]*vv[0] + M[4*i+1]*vv[1] + M[4*i+2]*vv[2] + M[4*i+3]*vv[3] + 1e-8f);
#pragma unroll
            for (int j2 = 0; j2 < 4; ++j2)
                vv[j2] = __builtin_amdgcn_rcpf(
                    M[j2]*u[0] + M[4+j2]*u[1] + M[8+j2]*u[2] + M[12+j2]*u[3] + 1e-8f);
        }

        if (tid < 16) {                    // C[m][n] = Hpost[m]*Hpre[n] + P[m][n]
            const int m = tid >> 2, n = tid & 3;
            Cs[tid] = Hpost[m] * Hpre[n] + u[m] * M[tid] * vv[n];
        }
    }
    __syncthreads();

    float C[16];
#pragma unroll
    for (int k = 0; k < 16; ++k) C[k] = Cs[k];       // wave-uniform broadcast

    float* orow = out + (size_t)row * NC;

    // segment A from prefetched registers
#pragma unroll
    for (int m = 0; m < 4; ++m) {
        float4 oA;
        oA.x = C[4*m+0]*hA[0].x + C[4*m+1]*hA[1].x + C[4*m+2]*hA[2].x + C[4*m+3]*hA[3].x;
        oA.y = C[4*m+0]*hA[0].y + C[4*m+1]*hA[1].y + C[4*m+2]*hA[2].y + C[4*m+3]*hA[3].y;
        oA.z = C[4*m+0]*hA[0].z + C[4*m+1]*hA[1].z + C[4*m+2]*hA[2].z + C[4*m+3]*hA[3].z;
        oA.w = C[4*m+0]*hA[0].w + C[4*m+1]*hA[1].w + C[4*m+2]*hA[2].w + C[4*m+3]*hA[3].w;
        *reinterpret_cast<float4*>(orow + m * D_ + d0) = oA;
    }

    // segment B inline (loads issue together, overlap with A-stores)
    float4 hB[4];
#pragma unroll
    for (int n = 0; n < 4; ++n)
        hB[n] = *reinterpret_cast<const float4*>(hr + n * D_ + d1);
#pragma unroll
    for (int m = 0; m < 4; ++m) {
        float4 oB;
        oB.x = C[4*m+0]*hB[0].x + C[4*m+1]*hB[1].x + C[4*m+2]*hB[2].x + C[4*m+3]*hB[3].x;
        oB.y = C[4*m+0]*hB[0].y + C[4*m+1]*hB[1].y + C[4*m+2]*hB[2].y + C[4*m+3]*hB[3].y;
        oB.z = C[4*m+0]*hB[0].z + C[4*m+1]*hB[1].z + C[4*m+2]*hB[2].z + C[4*m+3]*hB[3].z;
        oB.w = C[4*m+0]*hB[0].w + C[4*m+1]*hB[1].w + C[4*m+2]*hB[2].w + C[4*m+3]*hB[3].w;
        *reinterpret_cast<float4*>(orow + m * D_ + d1) = oB;
    }
}

// ======================= fallback (round-2, known-passing) =======================

__global__ void prep_w_kernel(const float* __restrict__ w, float* __restrict__ wp) {
    int idx = blockIdx.x * blockDim.x + threadIdx.x;
    if (idx >= NOUTS * NC) return;
    int o = idx / NC;
    int c = idx - o * NC;
    wp[o * WPAD + c] = w[c * NOUTS + o];
}

__global__ __launch_bounds__(256, 4) void fused_kernel(
    const float* __restrict__ h, const float* __restrict__ gamma,
    const float* __restrict__ wp, const float* __restrict__ alpha,
    const float* __restrict__ beta, const int* __restrict__ it_ptr,
    float* __restrict__ out, int nrows)
{
    const int wave = threadIdx.x >> 6;
    const int lane = threadIdx.x & 63;
    const int row  = (blockIdx.x << 2) | wave;
    if (row >= nrows) return;
    const float* hrow = h + (size_t)row * NC;

    float acc[NOUTS];
#pragma unroll
    for (int o = 0; o < NOUTS; ++o) acc[o] = 0.0f;
    float sumsq = 0.0f;
    const int base = lane << 2;
#pragma unroll 2
    for (int j = 0; j < 32; ++j) {
        const int c0 = base + (j << 8);
        const float4 h4 = *reinterpret_cast<const float4*>(hrow + c0);
        const float4 g4 = *reinterpret_cast<const float4*>(gamma + c0);
        sumsq += h4.x*h4.x + h4.y*h4.y + h4.z*h4.z + h4.w*h4.w;
        const float v0 = h4.x*g4.x, v1 = h4.y*g4.y, v2 = h4.z*g4.z, v3 = h4.w*g4.w;
#pragma unroll
        for (int o = 0; o < NOUTS; ++o) {
            const float4 w4 = *reinterpret_cast<const float4*>(wp + o * WPAD + c0);
            acc[o] += v0*w4.x + v1*w4.y + v2*w4.z + v3*w4.w;
        }
    }
#pragma unroll
    for (int m = 1; m < 64; m <<= 1) {
        sumsq += __shfl_xor(sumsq, m, 64);
#pragma unroll
        for (int o = 0; o < NOUTS; ++o) acc[o] += __shfl_xor(acc[o], m, 64);
    }
    const float r_ = sqrtf((float)NC / sumsq);
    const float a0 = alpha[0], a1 = alpha[1], a2 = alpha[2];
    float Hpre[4], Hpost[4], M[16];
#pragma unroll
    for (int n = 0; n < 4; ++n) {
        const float x = r_ * acc[n] * a0 + beta[n];
        Hpre[n] = __builtin_amdgcn_rcpf(1.0f + __expf(-x));
        const float y = r_ * acc[4 + n] * a1 + beta[4 + n];
        Hpost[n] = 2.0f * __builtin_amdgcn_rcpf(1.0f + __expf(-y));
    }
#pragma unroll
    for (int k = 0; k < 16; ++k)
        M[k] = __expf(r_ * acc[8 + k] * a2 + beta[8 + k]);
    float u[4] = {1.f,1.f,1.f,1.f}, v[4] = {1.f,1.f,1.f,1.f};
    int iters = *it_ptr;
    if (iters < 0 || iters > 10000) {
        const float f = __int_as_float(iters);
        iters = (f >= 0.0f && f < 10000.0f) ? (int)f : 10;
    }
    for (int it = 0; it < iters; ++it) {
#pragma unroll
        for (int i = 0; i < 4; ++i)
            u[i] = __builtin_amdgcn_rcpf(M[4*i+0]*v[0] + M[4*i+1]*v[1] + M[4*i+2]*v[2] + M[4*i+3]*v[3] + 1e-8f);
#pragma unroll
        for (int j2 = 0; j2 < 4; ++j2)
            v[j2] = __builtin_amdgcn_rcpf(M[j2]*u[0] + M[4+j2]*u[1] + M[8+j2]*u[2] + M[12+j2]*u[3] + 1e-8f);
    }
    float P[16];
#pragma unroll
    for (int i = 0; i < 4; ++i)
#pragma unroll
        for (int j2 = 0; j2 < 4; ++j2)
            P[4*i + j2] = u[i] * M[4*i + j2] * v[j2];
    float* orow = out + (size_t)row * NC;
#pragma unroll 2
    for (int t = 0; t < 8; ++t) {
        const int d0 = base + (t << 8);
        float hn[4][4];
#pragma unroll
        for (int n = 0; n < 4; ++n) {
            const float4 x4 = *reinterpret_cast<const float4*>(hrow + n * D_ + d0);
            hn[n][0]=x4.x; hn[n][1]=x4.y; hn[n][2]=x4.z; hn[n][3]=x4.w;
        }
        float hp[4];
#pragma unroll
        for (int k = 0; k < 4; ++k)
            hp[k] = Hpre[0]*hn[0][k] + Hpre[1]*hn[1][k] + Hpre[2]*hn[2][k] + Hpre[3]*hn[3][k];
#pragma unroll
        for (int m = 0; m < 4; ++m) {
            float4 o4;
            o4.x = Hpost[m]*hp[0] + P[4*m+0]*hn[0][0] + P[4*m+1]*hn[1][0] + P[4*m+2]*hn[2][0] + P[4*m+3]*hn[3][0];
            o4.y = Hpost[m]*hp[1] + P[4*m+0]*hn[0][1] + P[4*m+1]*hn[1][1] + P[4*m+2]*hn[2][1] + P[4*m+3]*hn[3][1];
            o4.z = Hpost[m]*hp[2] + P[4*m+0]*hn[0][2] + P[4*m+1]*hn[1][2] + P[4*m+2]*hn[2][2] + P[4*m+3]*hn[3][2];
            o4.w = Hpost[m]*hp[3] + P[4*m+0]*hn[0][3] + P[4*m+1]*hn[1][3] + P[4*m+2]*hn[2][3] + P[4*m+3]*hn[3][3];
            *reinterpret_cast<float4*>(orow + m * D_ + d0) = o4;
        }
    }
}

// ======================= launch =======================

extern "C" void kernel_launch(void* const* d_in, const int* in_sizes, int n_in,
                              void* d_out, int out_size, void* d_ws, size_t ws_size,
                              hipStream_t stream) {
    const float* h     = (const float*)d_in[0];
    const float* gamma = (const float*)d_in[1];
    const float* w     = (const float*)d_in[2];
    const float* alpha = (const float*)d_in[3];
    const float* beta  = (const float*)d_in[4];
    const int*   itp   = (const int*)d_in[5];
    float*       out   = (float*)d_out;

    const int nrows = in_sizes[0] / NC;                       // 4096

    const size_t wb_bytes = (size_t)NB * NC * 2;              // 512 KB bf16 w
    const size_t c_bytes  = (size_t)nrows * 16 * 4;           // 256 KB (slack)

    int nslices = 0;
    if ((nrows % 16) == 0) {
        for (int cand = 16; cand >= 4; cand >>= 1) {          // 16 = measured best
            const size_t pb = (size_t)cand * 25 * nrows * 4;
            if (ws_size >= wb_bytes + pb + c_bytes) { nslices = cand; break; }
        }
    }

    if (nslices) {
        uint16_t* wb   = (uint16_t*)d_ws;
        float*    part = (float*)((char*)d_ws + wb_bytes);

        prep_wb_kernel<<<(NB * NC + 255) / 256, 256, 0, stream>>>(w, gamma, wb);
        if (nslices == 16 && (nrows % 64) == 0) {
            // LDS path: 4 waves/block share one slice; nrg % 4 == 0 guaranteed.
            const int units = (nrows / 16) * 16;
            gemv_mfma_lds_kernel<<<units / 4, 256, 0, stream>>>(h, wb, part, nrows);
        } else {
            const int units = (nrows / 16) * nslices;
            gemv_mfma_kernel<<<(units + 3) / 4, 256, 0, stream>>>(h, wb, part, nrows, nslices);
        }
        sinkmix_kernel<<<nrows, 256, 0, stream>>>(h, part, alpha, beta, itp, out, nrows, nslices);
    } else {
        float* wp = (float*)d_ws;
        prep_w_kernel<<<(NOUTS * NC + 255) / 256, 256, 0, stream>>>(w, wp);
        fused_kernel<<<(nrows + 3) / 4, 256, 0, stream>>>(h, gamma, wp, alpha, beta, itp, out, nrows);
    }
}